// Round 6
// baseline (1465.116 us; speedup 1.0000x reference)
//
#include <hip/hip_runtime.h>
#include <math.h>

// Problem constants (match reference)
namespace {
constexpr int B_   = 8;
constexpr int M_   = 512;
constexpr int N_   = 1024;
constexpr int DTS  = 1024;
constexpr int DLLM = 4096;
constexpr int H_   = 16;
constexpr int E_   = 64;
constexpr int HE   = H_ * E_;   // 1024
// Finite stand-in for -inf in scores_for_log.
constexpr float NEG_BIG = -3.0e38f;
}

typedef __attribute__((ext_vector_type(4))) float f32x4;
typedef __attribute__((ext_vector_type(8))) short short8;
typedef unsigned int uint;
typedef unsigned short ushort;

// RNE split x = hi + lo (both representable as bf16; lo truncated).
__device__ inline void bsplit(float x, ushort& h, ushort& l) {
  uint u = __float_as_uint(x);
  uint hr = (u + 0x7FFFu + ((u >> 16) & 1u)) & 0xFFFF0000u;
  float lof = x - __uint_as_float(hr);
  h = (ushort)(hr >> 16);
  l = (ushort)(__float_as_uint(lof) >> 16);
}
__device__ inline uint pk(ushort a, ushort b) { return (uint)a | ((uint)b << 16); }

// async 16B global->LDS (m97-verified path)
__device__ inline void gld16(const void* g, void* l) {
  __builtin_amdgcn_global_load_lds(
      (const __attribute__((address_space(1))) uint*)g,
      (__attribute__((address_space(3))) uint*)l, 16, 0, 0);
}

// 16B global->VGPR via inline asm (compiler can't sink/hoist the wait we own)
__device__ __forceinline__ void gload16(short8& d, const ushort* p) {
  asm volatile("global_load_dwordx4 %0, %1, off"
               : "=v"(d) : "v"(p) : "memory");
}

// ---------------------------------------------------------------------------
// One-shot elementwise fp32 -> bf16 hi/lo split (row-major, no transpose).
// ---------------------------------------------------------------------------
__global__ __launch_bounds__(256) void asplit_kernel(
    const float* __restrict__ X, ushort* __restrict__ Xh,
    ushort* __restrict__ Xl, int n8) {
  const int idx = blockIdx.x * 256 + threadIdx.x;
  if (idx >= n8) return;
  const float4 a = *(const float4*)(X + (size_t)idx * 8);
  const float4 b = *(const float4*)(X + (size_t)idx * 8 + 4);
  float f[8] = {a.x, a.y, a.z, a.w, b.x, b.y, b.z, b.w};
  short8 h, l;
#pragma unroll
  for (int j = 0; j < 8; ++j) {
    ushort hh, ll;
    bsplit(f[j], hh, ll);
    h[j] = (short)hh;
    l[j] = (short)ll;
  }
  *(short8*)(Xh + (size_t)idx * 8) = h;
  *(short8*)(Xl + (size_t)idx * 8) = l;
}

// ---------------------------------------------------------------------------
// Weight transpose + bf16 split: W fp32 [K][N] -> Wth, Wtl bf16 [N][K].
// ---------------------------------------------------------------------------
__global__ __launch_bounds__(256) void tsplit_kernel(
    const float* __restrict__ W, ushort* __restrict__ Wth,
    ushort* __restrict__ Wtl, int K, int Nc) {
  __shared__ float S[32][33];
  const int t = threadIdx.x;
  const int n0 = blockIdx.x * 32, k0 = blockIdx.y * 32;
  const int c = t & 31, r8 = t >> 5;
#pragma unroll
  for (int i = 0; i < 4; ++i) {
    const int rr = r8 + i * 8;
    S[rr][c] = W[(size_t)(k0 + rr) * Nc + n0 + c];
  }
  __syncthreads();
#pragma unroll
  for (int i = 0; i < 4; ++i) {
    const int nn = r8 + i * 8;
    const float x = S[c][nn];
    ushort h, l;
    bsplit(x, h, l);
    const size_t o = (size_t)(n0 + nn) * K + k0 + c;
    Wth[o] = h;
    Wtl[o] = l;
  }
}

// ---------------------------------------------------------------------------
// V transpose prep: V fp32 [b*n][HE] -> Vth/Vtl bf16 [(b*H+h)*64+e][N].
// ---------------------------------------------------------------------------
__global__ __launch_bounds__(256) void vtprep_kernel(
    const float* __restrict__ V, ushort* __restrict__ Vth,
    ushort* __restrict__ Vtl) {
  __shared__ float S[64][68];
  const int t  = threadIdx.x;
  const int nt = blockIdx.x & 15;
  const int h  = (blockIdx.x >> 4) & 15;
  const int b  = blockIdx.x >> 8;
  const int n0 = nt * 64;
#pragma unroll
  for (int i = 0; i < 4; ++i) {
    const int idx = i * 256 + t;
    const int row = idx >> 4, c4 = (idx & 15) * 4;
    *(float4*)&S[row][c4] =
        *(const float4*)&V[(size_t)(b * N_ + n0 + row) * HE + h * 64 + c4];
  }
  __syncthreads();
  const int e = t >> 2, nch = (t & 3) * 16;
  short8 h0, h1, l0, l1;
#pragma unroll
  for (int j = 0; j < 8; ++j) {
    ushort hh, ll;
    bsplit(S[nch + j][e], hh, ll);
    h0[j] = (short)hh; l0[j] = (short)ll;
    bsplit(S[nch + 8 + j][e], hh, ll);
    h1[j] = (short)hh; l1[j] = (short)ll;
  }
  const size_t off = (size_t)((b * H_ + h) * 64 + e) * N_ + n0 + nch;
  *(short8*)(Vth + off)     = h0;
  *(short8*)(Vth + off + 8) = h1;
  *(short8*)(Vtl + off)     = l0;
  *(short8*)(Vtl + off + 8) = l1;
}

// ---------------------------------------------------------------------------
// bf16x3 split MFMA GEMM, fp32 A converted in-loop (verified fallback path).
// ---------------------------------------------------------------------------
template <bool ROWMASK, bool SPLITOUT>
__global__ __launch_bounds__(256) void gemm_split3_kernel(
    const float* __restrict__ A, const ushort* __restrict__ Bth,
    const ushort* __restrict__ Btl, const float* __restrict__ bias,
    const float* __restrict__ rowmask, float* __restrict__ C,
    ushort* __restrict__ Ch, ushort* __restrict__ Cl, int Kd, int Nc) {
  __shared__ ushort Ah[128][32];
  __shared__ ushort Al[128][32];
  __shared__ ushort Bh[128][32];
  __shared__ ushort Bl[128][32];

  const int t    = threadIdx.x;
  const int lane = t & 63;
  const int wv   = t >> 6;
  const int l15  = lane & 15;
  const int quad = lane >> 4;
  const int wm   = (wv & 1) * 64;
  const int wn   = (wv >> 1) * 64;
  const int row0 = blockIdx.y * 128;
  const int col0 = blockIdx.x * 128;

  const int arow = t >> 1;
  const int half = t & 1;
  const float* Ap = A + (size_t)(row0 + arow) * Kd + half * 16;

  const int bn  = (lane >> 2);
  const int bk8 = (lane & 3) * 8;
  const ushort* Bhp = Bth + (size_t)(col0 + wv * 32 + bn) * Kd + bk8;
  const ushort* Blp = Btl + (size_t)(col0 + wv * 32 + bn) * Kd + bk8;

  f32x4 acc[4][4];
#pragma unroll
  for (int i = 0; i < 4; ++i)
#pragma unroll
    for (int j = 0; j < 4; ++j) acc[i][j] = {0.f, 0.f, 0.f, 0.f};

  for (int k0 = 0; k0 < Kd; k0 += 32) {
    __syncthreads();
#pragma unroll
    for (int j = 0; j < 2; ++j) {
      const int n = wv * 32 + j * 16 + bn;
      gld16(Bhp + (size_t)j * 16 * Kd + k0, &Bh[n][bk8]);
      gld16(Blp + (size_t)j * 16 * Kd + k0, &Bl[n][bk8]);
    }
    float f[16];
#pragma unroll
    for (int i = 0; i < 4; ++i) {
      const float4 v = *(const float4*)(Ap + k0 + i * 4);
      f[i * 4 + 0] = v.x; f[i * 4 + 1] = v.y;
      f[i * 4 + 2] = v.z; f[i * 4 + 3] = v.w;
    }
    ushort hh[16], ll[16];
#pragma unroll
    for (int i = 0; i < 16; ++i) bsplit(f[i], hh[i], ll[i]);
    uint4 wh0 = {pk(hh[0], hh[1]), pk(hh[2], hh[3]), pk(hh[4], hh[5]), pk(hh[6], hh[7])};
    uint4 wh1 = {pk(hh[8], hh[9]), pk(hh[10], hh[11]), pk(hh[12], hh[13]), pk(hh[14], hh[15])};
    uint4 wl0 = {pk(ll[0], ll[1]), pk(ll[2], ll[3]), pk(ll[4], ll[5]), pk(ll[6], ll[7])};
    uint4 wl1 = {pk(ll[8], ll[9]), pk(ll[10], ll[11]), pk(ll[12], ll[13]), pk(ll[14], ll[15])};
    *(uint4*)&Ah[arow][half * 16 + 0] = wh0;
    *(uint4*)&Ah[arow][half * 16 + 8] = wh1;
    *(uint4*)&Al[arow][half * 16 + 0] = wl0;
    *(uint4*)&Al[arow][half * 16 + 8] = wl1;

    __syncthreads();

    short8 ah[4], al[4], bh[4], bl[4];
#pragma unroll
    for (int mi = 0; mi < 4; ++mi) {
      ah[mi] = *(const short8*)&Ah[wm + mi * 16 + l15][quad * 8];
      al[mi] = *(const short8*)&Al[wm + mi * 16 + l15][quad * 8];
    }
#pragma unroll
    for (int ni = 0; ni < 4; ++ni) {
      bh[ni] = *(const short8*)&Bh[wn + ni * 16 + l15][quad * 8];
      bl[ni] = *(const short8*)&Bl[wn + ni * 16 + l15][quad * 8];
    }
#pragma unroll
    for (int mi = 0; mi < 4; ++mi)
#pragma unroll
      for (int ni = 0; ni < 4; ++ni) {
        acc[mi][ni] = __builtin_amdgcn_mfma_f32_16x16x32_bf16(
            ah[mi], bh[ni], acc[mi][ni], 0, 0, 0);
        acc[mi][ni] = __builtin_amdgcn_mfma_f32_16x16x32_bf16(
            ah[mi], bl[ni], acc[mi][ni], 0, 0, 0);
        acc[mi][ni] = __builtin_amdgcn_mfma_f32_16x16x32_bf16(
            al[mi], bh[ni], acc[mi][ni], 0, 0, 0);
      }
  }

  float bb[4];
#pragma unroll
  for (int ni = 0; ni < 4; ++ni) bb[ni] = bias[col0 + wn + ni * 16 + l15];
#pragma unroll
  for (int mi = 0; mi < 4; ++mi)
#pragma unroll
    for (int r = 0; r < 4; ++r) {
      const int row = row0 + wm + mi * 16 + quad * 4 + r;
      const float rm = ROWMASK ? rowmask[row] : 1.f;
#pragma unroll
      for (int ni = 0; ni < 4; ++ni) {
        const int col = col0 + wn + ni * 16 + l15;
        float v = acc[mi][ni][r] + bb[ni];
        if (SPLITOUT) {
          ushort vh, vl;
          bsplit(v, vh, vl);
          Ch[(size_t)row * Nc + col] = vh;
          Cl[(size_t)row * Nc + col] = vl;
        } else {
          if (ROWMASK) v *= rm;
          C[(size_t)row * Nc + col] = v;
        }
      }
    }
}

// ---------------------------------------------------------------------------
// R6: bf16x3 split MFMA GEMM, A via LDS (chunk-XOR swizzled), B fragments
// DIRECT global->VGPR (pre-transposed [N][K] makes each lane's B-frag 16B
// contiguous). Halves LDS pipe traffic (R5 diagnosis: LDS port saturated at
// ~1.65x the MFMA window -> MfmaUtil pinned at 37%). B regs double-buffered
// one K-substep ahead via inline-asm loads + counted vmcnt(8); sched_barrier
// after each waitcnt (rule #18). XCD-aware remap kept (FETCH 944->144 MB).
// ---------------------------------------------------------------------------
#define LOADB8(SH, SL, KK)          \
  gload16(SH[0], bhp0 + (KK));      \
  gload16(SH[1], bhp1 + (KK));      \
  gload16(SH[2], bhp2 + (KK));      \
  gload16(SH[3], bhp3 + (KK));      \
  gload16(SL[0], blp0 + (KK));      \
  gload16(SL[1], blp1 + (KK));      \
  gload16(SL[2], blp2 + (KK));      \
  gload16(SL[3], blp3 + (KK));

#define STAGEA(KK)                                      \
  _Pragma("unroll")                                     \
  for (int j = 0; j < 2; ++j) {                         \
    const int rr = wv * 32 + j * 16;                    \
    const size_t o = (size_t)j * 16 * Kd + (KK);        \
    gld16(Ahp + o, &Ah[rr][0]);                         \
    gld16(Alp + o, &Al[rr][0]);                         \
  }

#define SYNC_TOP()                                      \
  asm volatile("s_waitcnt vmcnt(8)" ::: "memory");      \
  __builtin_amdgcn_sched_barrier(0);                    \
  __builtin_amdgcn_s_barrier();                         \
  __builtin_amdgcn_sched_barrier(0);

#define SYNC_BOT()                                      \
  __builtin_amdgcn_sched_barrier(0);                    \
  asm volatile("s_waitcnt lgkmcnt(0)" ::: "memory");    \
  __builtin_amdgcn_s_barrier();                         \
  __builtin_amdgcn_sched_barrier(0);

#define COMPUTE(BH, BL)                                                     \
  {                                                                         \
    short8 ah[4], al[4];                                                    \
    _Pragma("unroll")                                                       \
    for (int mi = 0; mi < 4; ++mi) {                                        \
      ah[mi] = *(const short8*)&Ah[wm + mi * 16 + l15][fsw];                \
      al[mi] = *(const short8*)&Al[wm + mi * 16 + l15][fsw];                \
    }                                                                       \
    __builtin_amdgcn_s_setprio(1);                                          \
    _Pragma("unroll")                                                       \
    for (int mi = 0; mi < 4; ++mi)                                          \
      _Pragma("unroll")                                                     \
      for (int ni = 0; ni < 4; ++ni) {                                      \
        acc[mi][ni] = __builtin_amdgcn_mfma_f32_16x16x32_bf16(              \
            ah[mi], BH[ni], acc[mi][ni], 0, 0, 0);                          \
        acc[mi][ni] = __builtin_amdgcn_mfma_f32_16x16x32_bf16(              \
            ah[mi], BL[ni], acc[mi][ni], 0, 0, 0);                          \
        acc[mi][ni] = __builtin_amdgcn_mfma_f32_16x16x32_bf16(              \
            al[mi], BH[ni], acc[mi][ni], 0, 0, 0);                          \
      }                                                                     \
    __builtin_amdgcn_s_setprio(0);                                          \
  }

template <bool ROWMASK, bool SPLITOUT>
__global__ __launch_bounds__(256) void gemm_breg_kernel(
    const ushort* __restrict__ Ath, const ushort* __restrict__ Atl,
    const ushort* __restrict__ Bth, const ushort* __restrict__ Btl,
    const float* __restrict__ bias, const float* __restrict__ rowmask,
    float* __restrict__ C, ushort* __restrict__ Ch, ushort* __restrict__ Cl,
    int Kd, int Nc, int gx) {
  __shared__ ushort Ah[128][32];   // 8 KB
  __shared__ ushort Al[128][32];   // 8 KB

  const int t    = threadIdx.x;
  const int lane = t & 63;
  const int wv   = t >> 6;
  const int l15  = lane & 15;
  const int quad = lane >> 4;
  const int wm   = (wv & 1) * 64;
  const int wn   = (wv >> 1) * 64;

  // XCD-aware decode: lin = (yb%8) + 8*xb + 8*gx*(yb/8)  (bijective)
  const int lin  = blockIdx.x;
  const int xb   = (lin >> 3) % gx;
  const int yb   = (lin & 7) + 8 * ((lin >> 3) / gx);
  const int row0 = yb * 128;
  const int col0 = xb * 128;

  // A staging: lane -> (row srow, chunk lane&3); source chunk inverse-swizzled
  const int srow = lane >> 2;
  const int sch8 = ((lane & 3) ^ (srow & 3)) * 8;
  const ushort* Ahp = Ath + (size_t)(row0 + wv * 32 + srow) * Kd + sch8;
  const ushort* Alp = Atl + (size_t)(row0 + wv * 32 + srow) * Kd + sch8;

  // A fragment read: chunk = quad ^ (row&3); row&3 == l15&3
  const int fsw = (quad ^ (l15 & 3)) * 8;

  // B fragment bases (per-lane 16B contiguous in pre-transposed [N][K])
  const ushort* bhp0 = Bth + (size_t)(col0 + wn +  0 + l15) * Kd + quad * 8;
  const ushort* bhp1 = Bth + (size_t)(col0 + wn + 16 + l15) * Kd + quad * 8;
  const ushort* bhp2 = Bth + (size_t)(col0 + wn + 32 + l15) * Kd + quad * 8;
  const ushort* bhp3 = Bth + (size_t)(col0 + wn + 48 + l15) * Kd + quad * 8;
  const ushort* blp0 = Btl + (size_t)(col0 + wn +  0 + l15) * Kd + quad * 8;
  const ushort* blp1 = Btl + (size_t)(col0 + wn + 16 + l15) * Kd + quad * 8;
  const ushort* blp2 = Btl + (size_t)(col0 + wn + 32 + l15) * Kd + quad * 8;
  const ushort* blp3 = Btl + (size_t)(col0 + wn + 48 + l15) * Kd + quad * 8;

  f32x4 acc[4][4];
#pragma unroll
  for (int i = 0; i < 4; ++i)
#pragma unroll
    for (int j = 0; j < 4; ++j) acc[i][j] = {0.f, 0.f, 0.f, 0.f};

  short8 b0h[4], b0l[4], b1h[4], b1l[4];

  // prologue: B(k=0) -> set0  (outstanding 8)
  LOADB8(b0h, b0l, 0);

  // Kd/32 is even for all call sites (4096, 1024) -> 2 substeps per iter.
  for (int k0 = 0; k0 < Kd; k0 += 64) {
    // substep 0: compute k0 with set0; prefetch set1 <- k0+32
    STAGEA(k0);                       // +4 (12 outstanding)
    LOADB8(b1h, b1l, k0 + 32);        // +8 (20)
    SYNC_TOP();                       // vmcnt(8): set0 + A(k0) done
    COMPUTE(b0h, b0l);
    SYNC_BOT();

    // substep 1: compute k0+32 with set1; prefetch set0 <- k0+64 (clamped)
    STAGEA(k0 + 32);
    const int kn = (k0 + 64 < Kd) ? k0 + 64 : 0;   // clamped, dead on last
    LOADB8(b0h, b0l, kn);
    SYNC_TOP();                       // vmcnt(8): set1 + A(k0+32) done
    COMPUTE(b1h, b1l);
    SYNC_BOT();
  }

  float bb[4];
#pragma unroll
  for (int ni = 0; ni < 4; ++ni) bb[ni] = bias[col0 + wn + ni * 16 + l15];
#pragma unroll
  for (int mi = 0; mi < 4; ++mi)
#pragma unroll
    for (int r = 0; r < 4; ++r) {
      const int row = row0 + wm + mi * 16 + quad * 4 + r;
      const float rm = ROWMASK ? rowmask[row] : 1.f;
#pragma unroll
      for (int ni = 0; ni < 4; ++ni) {
        const int col = col0 + wn + ni * 16 + l15;
        float v = acc[mi][ni][r] + bb[ni];
        if (SPLITOUT) {
          ushort vh, vl;
          bsplit(v, vh, vl);
          Ch[(size_t)row * Nc + col] = vh;
          Cl[(size_t)row * Nc + col] = vl;
        } else {
          if (ROWMASK) v *= rm;
          C[(size_t)row * Nc + col] = v;
        }
      }
    }
}

#undef LOADB8
#undef STAGEA
#undef SYNC_TOP
#undef SYNC_BOT
#undef COMPUTE

// ---------------------------------------------------------------------------
// MFMA flash attention. Block = (b, h, 64 q-rows); 4 waves x 16 rows.
// ---------------------------------------------------------------------------
__global__ __launch_bounds__(256) void attn_mfma_kernel(
    const ushort* __restrict__ Qh, const ushort* __restrict__ Ql,
    const ushort* __restrict__ Kh, const ushort* __restrict__ Kl,
    const ushort* __restrict__ Vth, const ushort* __restrict__ Vtl,
    const unsigned char* __restrict__ kvmask, const float* __restrict__ tsmask,
    float* __restrict__ outv, float* __restrict__ scores_out) {
  __shared__ __align__(16) ushort sm[24576];  // 48 KB
  ushort* KHT = sm;            // [64 rows(n)][64 e] swizzled
  ushort* KLT = sm + 4096;
  ushort* VTH = sm + 8192;     // [64 rows(e)][64 n] swizzled
  ushort* VTL = sm + 12288;
  ushort* QHT = sm + 16384;    // [64 rows(m)][64 e] swizzled (dead after frag read)
  ushort* QLT = sm + 20480;

  const int t = threadIdx.x, lane = t & 63, wv = t >> 6;
  const int l15 = lane & 15, quad = lane >> 4;
  const int blk = blockIdx.x;          // b*128 + h*8 + mt
  const int mt = blk & 7;
  const int h  = (blk >> 3) & 15;
  const int b  = blk >> 7;
  const int m0 = mt * 64;
  const int lrow = lane >> 3, lch = lane & 7;
  const int gch8 = (lch ^ (lrow & 7)) * 8;  // swizzled 16B-chunk, ushort offset

  // ---- stage Q tile (wave wv: rows wv*16..+15), hi and lo ----
#pragma unroll
  for (int i = 0; i < 2; ++i) {
    const int rr = wv * 16 + i * 8;   // wave-uniform LDS row base
    const size_t g = (size_t)(b * M_ + m0 + rr + lrow) * HE + h * 64 + gch8;
    gld16(Qh + g, &QHT[rr * 64]);
    gld16(Ql + g, &QLT[rr * 64]);
  }
  __syncthreads();

  short8 qh[2], ql[2];
#pragma unroll
  for (int ks = 0; ks < 2; ++ks) {
    const int row = wv * 16 + l15;
    const int off = row * 64 + (((ks * 4 + quad) ^ (row & 7)) << 3);
    qh[ks] = *(const short8*)&QHT[off];
    ql[ks] = *(const short8*)&QLT[off];
  }
  __builtin_amdgcn_s_waitcnt(0);  // Q frag reads complete before Pu aliases region

  uint* Pu = (uint*)(sm + 16384) + wv * 1024;  // per-wave P, packed hi|lo

  float tsm_v[4];
#pragma unroll
  for (int r = 0; r < 4; ++r)
    tsm_v[r] = tsmask[b * M_ + m0 + wv * 16 + quad * 4 + r];

  float m_i[4] = {-INFINITY, -INFINITY, -INFINITY, -INFINITY};
  float l_i[4] = {0.f, 0.f, 0.f, 0.f};
  f32x4 acc[4];
#pragma unroll
  for (int es = 0; es < 4; ++es) acc[es] = {0.f, 0.f, 0.f, 0.f};

  for (int nc = 0; nc < 16; ++nc) {
    const int n0 = nc * 64;
    __syncthreads();  // prev iter's LDS reads done (iter0: Q frag reads done)
    // ---- stage K rows / V^T rows (wave wv: rows wv*16..+15 of each) ----
#pragma unroll
    for (int i = 0; i < 2; ++i) {
      const int rr = wv * 16 + i * 8;
      const size_t gk = (size_t)(b * N_ + n0 + rr + lrow) * HE + h * 64 + gch8;
      const size_t gv = (size_t)((b * H_ + h) * 64 + rr + lrow) * N_ + n0 + gch8;
      gld16(Kh + gk, &KHT[rr * 64]);
      gld16(Kl + gk, &KLT[rr * 64]);
      gld16(Vth + gv, &VTH[rr * 64]);
      gld16(Vtl + gv, &VTL[rr * 64]);
    }
    __syncthreads();  // drains vmcnt

    // ---- S = Q K^T (split3) ----
    f32x4 s[4];
#pragma unroll
    for (int ns = 0; ns < 4; ++ns) {
      s[ns] = {0.f, 0.f, 0.f, 0.f};
#pragma unroll
      for (int ks = 0; ks < 2; ++ks) {
        const int row = ns * 16 + l15;
        const int off = row * 64 + (((ks * 4 + quad) ^ (row & 7)) << 3);
        const short8 kh = *(const short8*)&KHT[off];
        const short8 kl = *(const short8*)&KLT[off];
        s[ns] = __builtin_amdgcn_mfma_f32_16x16x32_bf16(qh[ks], kh, s[ns], 0, 0, 0);
        s[ns] = __builtin_amdgcn_mfma_f32_16x16x32_bf16(qh[ks], kl, s[ns], 0, 0, 0);
        s[ns] = __builtin_amdgcn_mfma_f32_16x16x32_bf16(ql[ks], kh, s[ns], 0, 0, 0);
      }
    }

    // ---- scale + mask ----
    bool km[4];
#pragma unroll
    for (int ns = 0; ns < 4; ++ns)
      km[ns] = kvmask[b * N_ + n0 + ns * 16 + l15] != 0;
    float sc[4][4];  // [reg r][ns]
#pragma unroll
    for (int ns = 0; ns < 4; ++ns)
#pragma unroll
      for (int r = 0; r < 4; ++r)
        sc[r][ns] = km[ns] ? -INFINITY : s[ns][r] * 0.125f;

    // ---- scores_for_log ----
#pragma unroll
    for (int r = 0; r < 4; ++r) {
      const size_t base =
          ((size_t)(b * H_ + h) * M_ + m0 + wv * 16 + quad * 4 + r) * N_ + n0;
      const bool vr = tsm_v[r] != 0.f;
#pragma unroll
      for (int ns = 0; ns < 4; ++ns)
        scores_out[base + ns * 16 + l15] =
            (vr && !km[ns]) ? sc[r][ns] : NEG_BIG;
    }

    // ---- online softmax + P pack to LDS ----
#pragma unroll
    for (int r = 0; r < 4; ++r) {
      float cm = fmaxf(fmaxf(sc[r][0], sc[r][1]), fmaxf(sc[r][2], sc[r][3]));
#pragma unroll
      for (int o = 1; o < 16; o <<= 1) cm = fmaxf(cm, __shfl_xor(cm, o));
      const float nm = fmaxf(m_i[r], cm);
      const float alpha = (m_i[r] == -INFINITY) ? 0.f : __expf(m_i[r] - nm);
      float ps = 0.f;
      const int pr = quad * 4 + r;
#pragma unroll
      for (int ns = 0; ns < 4; ++ns) {
        const float p = (sc[r][ns] == -INFINITY) ? 0.f : __expf(sc[r][ns] - nm);
        ps += p;
        ushort ph_, pl_;
        bsplit(p, ph_, pl_);
        const int c = ns * 16 + l15;
        Pu[pr * 64 + (((c >> 2) ^ (pr & 7)) << 2) + (c & 3)] = pk(ph_, pl_);
      }
#pragma unroll
      for (int o = 1; o < 16; o <<= 1) ps += __shfl_xor(ps, o);
      l_i[r] = l_i[r] * alpha + ps;
      m_i[r] = nm;
#pragma unroll
      for (int es = 0; es < 4; ++es) acc[es][r] *= alpha;
    }

    // ---- PV (split3); P A-frag from packed LDS, V^T B-frag ----
#pragma unroll
    for (int ks = 0; ks < 2; ++ks) {
      const int c0 = ks * 8 + quad * 2;
      const uint* pb = &Pu[l15 * 64];
      const uint4 u0 = *(const uint4*)&pb[(c0 ^ (l15 & 7)) << 2];
      const uint4 u1 = *(const uint4*)&pb[((c0 + 1) ^ (l15 & 7)) << 2];
      short8 ph, pl;
      const uint* up0 = (const uint*)&u0;
      const uint* up1 = (const uint*)&u1;
#pragma unroll
      for (int j = 0; j < 4; ++j) {
        ph[j] = (short)(up0[j] & 0xffffu); pl[j] = (short)(up0[j] >> 16);
        ph[4 + j] = (short)(up1[j] & 0xffffu); pl[4 + j] = (short)(up1[j] >> 16);
      }
#pragma unroll
      for (int es = 0; es < 4; ++es) {
        const int row = es * 16 + l15;
        const int off = row * 64 + (((ks * 4 + quad) ^ (row & 7)) << 3);
        const short8 vh = *(const short8*)&VTH[off];
        const short8 vl = *(const short8*)&VTL[off];
        acc[es] = __builtin_amdgcn_mfma_f32_16x16x32_bf16(ph, vh, acc[es], 0, 0, 0);
        acc[es] = __builtin_amdgcn_mfma_f32_16x16x32_bf16(ph, vl, acc[es], 0, 0, 0);
        acc[es] = __builtin_amdgcn_mfma_f32_16x16x32_bf16(pl, vh, acc[es], 0, 0, 0);
      }
    }
  }

  // ---- epilogue: out_v = acc / l ----
#pragma unroll
  for (int r = 0; r < 4; ++r) {
    const float inv = (l_i[r] > 0.f) ? 1.f / l_i[r] : 0.f;
    const int grow = b * M_ + m0 + wv * 16 + quad * 4 + r;
#pragma unroll
    for (int es = 0; es < 4; ++es)
      outv[(size_t)grow * HE + h * 64 + es * 16 + l15] = acc[es][r] * inv;
  }
}

// ---------------------------------------------------------------------------
extern "C" void kernel_launch(void* const* d_in, const int* in_sizes, int n_in,
                              void* d_out, int out_size, void* d_ws,
                              size_t ws_size, hipStream_t stream) {
  const float* ts  = (const float*)d_in[0];
  const float* kv  = (const float*)d_in[1];
  const float* tsm = (const float*)d_in[2];
  const unsigned char* kvm = (const unsigned char*)d_in[3];
  const float* Wq = (const float*)d_in[4];
  const float* bq = (const float*)d_in[5];
  const float* Wk = (const float*)d_in[6];
  const float* bk = (const float*)d_in[7];
  const float* Wv = (const float*)d_in[8];
  const float* bv = (const float*)d_in[9];
  const float* Wo = (const float*)d_in[10];
  const float* bo = (const float*)d_in[11];

  float* out        = (float*)d_out;
  float* scores_out = out + (size_t)B_ * M_ * DLLM;

  char* ws = (char*)d_ws;
  constexpr size_t MB = 1024 * 1024;

  if (ws_size >= 260 * MB) {
    // ---------- pre-split path (A operands staged as bf16 hi/lo) ----------
    ushort* Kvh  = (ushort*)(ws);
    ushort* Kvl  = (ushort*)(ws + 64 * MB);
    float*  Vf   = (float*)(ws + 128 * MB);
    ushort* Khp  = (ushort*)(ws + 160 * MB);
    ushort* Klp  = (ushort*)(ws + 176 * MB);
    ushort* Qhp  = (ushort*)(ws + 192 * MB);
    ushort* Qlp  = (ushort*)(ws + 200 * MB);
    ushort* Tsh  = (ushort*)(ws + 208 * MB);
    ushort* Tsl  = (ushort*)(ws + 216 * MB);
    ushort* Wqh  = (ushort*)(ws + 224 * MB);
    ushort* Wql  = (ushort*)(ws + 226 * MB);
    ushort* Wkh  = (ushort*)(ws + 228 * MB);
    ushort* Wkl  = (ushort*)(ws + 236 * MB);
    ushort* Wvh  = (ushort*)(ws + 244 * MB);
    ushort* Wvl  = (ushort*)(ws + 252 * MB);
    // aliases valid once predecessors are dead (stream-ordered)
    ushort* Vthp  = (ushort*)(ws);
    ushort* Vtlp  = (ushort*)(ws + 16 * MB);
    ushort* outvh = (ushort*)(ws + 32 * MB);
    ushort* outvl = (ushort*)(ws + 40 * MB);
    ushort* Woh   = (ushort*)(ws + 64 * MB);
    ushort* Wol   = (ushort*)(ws + 72 * MB);
    float*  outv  = (float*)(ws + 128 * MB);

    // input pre-splits
    {
      const int n8_ts = (B_ * M_ * DTS) / 8;     // 512K
      asplit_kernel<<<dim3(n8_ts / 256), 256, 0, stream>>>(ts, Tsh, Tsl, n8_ts);
      const int n8_kv = (B_ * N_ * DLLM) / 8;    // 4M
      asplit_kernel<<<dim3(n8_kv / 256), 256, 0, stream>>>(kv, Kvh, Kvl, n8_kv);
    }

    // weight transpose+split
    tsplit_kernel<<<dim3(HE / 32, DTS / 32), 256, 0, stream>>>(Wq, Wqh, Wql, DTS, HE);
    tsplit_kernel<<<dim3(HE / 32, DLLM / 32), 256, 0, stream>>>(Wk, Wkh, Wkl, DLLM, HE);
    tsplit_kernel<<<dim3(HE / 32, DLLM / 32), 256, 0, stream>>>(Wv, Wvh, Wvl, DLLM, HE);

    // projections (A in LDS, B direct-to-reg); 1D grid, XCD-aware decode
    gemm_breg_kernel<false, true><<<dim3((HE / 128) * ((B_ * M_) / 128)), 256, 0, stream>>>(
        Tsh, Tsl, Wqh, Wql, bq, nullptr, nullptr, Qhp, Qlp, DTS, HE, HE / 128);
    gemm_breg_kernel<false, true><<<dim3((HE / 128) * ((B_ * N_) / 128)), 256, 0, stream>>>(
        Kvh, Kvl, Wkh, Wkl, bk, nullptr, nullptr, Khp, Klp, DLLM, HE, HE / 128);
    gemm_breg_kernel<false, false><<<dim3((HE / 128) * ((B_ * N_) / 128)), 256, 0, stream>>>(
        Kvh, Kvl, Wvh, Wvl, bv, nullptr, Vf, nullptr, nullptr, DLLM, HE, HE / 128);

    // V^T split prep (Kv regions dead now; writes into [0,32))
    vtprep_kernel<<<dim3(B_ * H_ * 16), 256, 0, stream>>>(Vf, Vthp, Vtlp);

    // MFMA flash attention (+ scores_for_log); writes outv fp32 over dead Vf
    attn_mfma_kernel<<<dim3(B_ * H_ * (M_ / 64)), 256, 0, stream>>>(
        Qhp, Qlp, Khp, Klp, Vthp, Vtlp, kvm, tsm, outv, scores_out);

    // split attn output for pre-split O-GEMM
    {
      const int n8_o = (B_ * M_ * HE) / 8;       // 512K
      asplit_kernel<<<dim3(n8_o / 256), 256, 0, stream>>>(outv, outvh, outvl, n8_o);
    }

    // output projection
    tsplit_kernel<<<dim3(DLLM / 32, HE / 32), 256, 0, stream>>>(Wo, Woh, Wol, HE, DLLM);
    gemm_breg_kernel<true, false><<<dim3((DLLM / 128) * ((B_ * M_) / 128)), 256, 0, stream>>>(
        outvh, outvl, Woh, Wol, bo, tsm, out, nullptr, nullptr, HE, DLLM, DLLM / 128);
  } else {
    // ---------- fallback: exact verified baseline path (116 MB) ----------
    float*  Vf   = (float*)(ws);
    float*  outv = (float*)(ws);
    ushort* Qhp  = (ushort*)(ws + 32 * MB);
    ushort* Qlp  = (ushort*)(ws + 40 * MB);
    ushort* Khp  = (ushort*)(ws + 48 * MB);
    ushort* Klp  = (ushort*)(ws + 64 * MB);
    ushort* Wqh  = (ushort*)(ws + 80 * MB);
    ushort* Wql  = (ushort*)(ws + 82 * MB);
    ushort* Wkh  = (ushort*)(ws + 84 * MB);
    ushort* Wkl  = (ushort*)(ws + 92 * MB);
    ushort* Wvh  = (ushort*)(ws + 100 * MB);
    ushort* Wvl  = (ushort*)(ws + 108 * MB);
    ushort* Vthp = (ushort*)(ws + 84 * MB);
    ushort* Vtlp = (ushort*)(ws + 100 * MB);
    ushort* Woh  = (ushort*)(ws + 48 * MB);
    ushort* Wol  = (ushort*)(ws + 56 * MB);

    tsplit_kernel<<<dim3(HE / 32, DTS / 32), 256, 0, stream>>>(Wq, Wqh, Wql, DTS, HE);
    tsplit_kernel<<<dim3(HE / 32, DLLM / 32), 256, 0, stream>>>(Wk, Wkh, Wkl, DLLM, HE);
    tsplit_kernel<<<dim3(HE / 32, DLLM / 32), 256, 0, stream>>>(Wv, Wvh, Wvl, DLLM, HE);

    gemm_split3_kernel<false, true><<<dim3(HE / 128, (B_ * M_) / 128), 256, 0, stream>>>(
        ts, Wqh, Wql, bq, nullptr, nullptr, Qhp, Qlp, DTS, HE);
    gemm_split3_kernel<false, true><<<dim3(HE / 128, (B_ * N_) / 128), 256, 0, stream>>>(
        kv, Wkh, Wkl, bk, nullptr, nullptr, Khp, Klp, DLLM, HE);
    gemm_split3_kernel<false, false><<<dim3(HE / 128, (B_ * N_) / 128), 256, 0, stream>>>(
        kv, Wvh, Wvl, bv, nullptr, Vf, nullptr, nullptr, DLLM, HE);

    vtprep_kernel<<<dim3(B_ * H_ * 16), 256, 0, stream>>>(Vf, Vthp, Vtlp);

    attn_mfma_kernel<<<dim3(B_ * H_ * (M_ / 64)), 256, 0, stream>>>(
        Qhp, Qlp, Khp, Klp, Vthp, Vtlp, kvm, tsm, outv, scores_out);

    tsplit_kernel<<<dim3(DLLM / 32, HE / 32), 256, 0, stream>>>(Wo, Woh, Wol, HE, DLLM);
    gemm_split3_kernel<true, false><<<dim3(DLLM / 128, (B_ * M_) / 128), 256, 0, stream>>>(
        outv, Woh, Wol, bo, tsm, out, nullptr, nullptr, HE, DLLM);
  }
}

// Round 7
// 1408.124 us; speedup vs baseline: 1.0405x; 1.0405x over previous
//
#include <hip/hip_runtime.h>
#include <math.h>

// Problem constants (match reference)
namespace {
constexpr int B_   = 8;
constexpr int M_   = 512;
constexpr int N_   = 1024;
constexpr int DTS  = 1024;
constexpr int DLLM = 4096;
constexpr int H_   = 16;
constexpr int E_   = 64;
constexpr int HE   = H_ * E_;   // 1024
// Finite stand-in for -inf in scores_for_log.
constexpr float NEG_BIG = -3.0e38f;
}

typedef __attribute__((ext_vector_type(4))) float f32x4;
typedef __attribute__((ext_vector_type(8))) short short8;
typedef unsigned int uint;
typedef unsigned short ushort;

// RNE split x = hi + lo (both representable as bf16; lo truncated).
__device__ inline void bsplit(float x, ushort& h, ushort& l) {
  uint u = __float_as_uint(x);
  uint hr = (u + 0x7FFFu + ((u >> 16) & 1u)) & 0xFFFF0000u;
  float lof = x - __uint_as_float(hr);
  h = (ushort)(hr >> 16);
  l = (ushort)(__float_as_uint(lof) >> 16);
}
__device__ inline uint pk(ushort a, ushort b) { return (uint)a | ((uint)b << 16); }

// async 16B global->LDS (m97-verified path)
__device__ inline void gld16(const void* g, void* l) {
  __builtin_amdgcn_global_load_lds(
      (const __attribute__((address_space(1))) uint*)g,
      (__attribute__((address_space(3))) uint*)l, 16, 0, 0);
}

// ---------------------------------------------------------------------------
// One-shot elementwise fp32 -> bf16 hi/lo split (row-major, no transpose).
// ---------------------------------------------------------------------------
__global__ __launch_bounds__(256) void asplit_kernel(
    const float* __restrict__ X, ushort* __restrict__ Xh,
    ushort* __restrict__ Xl, int n8) {
  const int idx = blockIdx.x * 256 + threadIdx.x;
  if (idx >= n8) return;
  const float4 a = *(const float4*)(X + (size_t)idx * 8);
  const float4 b = *(const float4*)(X + (size_t)idx * 8 + 4);
  float f[8] = {a.x, a.y, a.z, a.w, b.x, b.y, b.z, b.w};
  short8 h, l;
#pragma unroll
  for (int j = 0; j < 8; ++j) {
    ushort hh, ll;
    bsplit(f[j], hh, ll);
    h[j] = (short)hh;
    l[j] = (short)ll;
  }
  *(short8*)(Xh + (size_t)idx * 8) = h;
  *(short8*)(Xl + (size_t)idx * 8) = l;
}

// ---------------------------------------------------------------------------
// Weight transpose + bf16 split: W fp32 [K][N] -> Wth, Wtl bf16 [N][K].
// ---------------------------------------------------------------------------
__global__ __launch_bounds__(256) void tsplit_kernel(
    const float* __restrict__ W, ushort* __restrict__ Wth,
    ushort* __restrict__ Wtl, int K, int Nc) {
  __shared__ float S[32][33];
  const int t = threadIdx.x;
  const int n0 = blockIdx.x * 32, k0 = blockIdx.y * 32;
  const int c = t & 31, r8 = t >> 5;
#pragma unroll
  for (int i = 0; i < 4; ++i) {
    const int rr = r8 + i * 8;
    S[rr][c] = W[(size_t)(k0 + rr) * Nc + n0 + c];
  }
  __syncthreads();
#pragma unroll
  for (int i = 0; i < 4; ++i) {
    const int nn = r8 + i * 8;
    const float x = S[c][nn];
    ushort h, l;
    bsplit(x, h, l);
    const size_t o = (size_t)(n0 + nn) * K + k0 + c;
    Wth[o] = h;
    Wtl[o] = l;
  }
}

// ---------------------------------------------------------------------------
// V transpose prep: V fp32 [b*n][HE] -> Vth/Vtl bf16 [(b*H+h)*64+e][N].
// ---------------------------------------------------------------------------
__global__ __launch_bounds__(256) void vtprep_kernel(
    const float* __restrict__ V, ushort* __restrict__ Vth,
    ushort* __restrict__ Vtl) {
  __shared__ float S[64][68];
  const int t  = threadIdx.x;
  const int nt = blockIdx.x & 15;
  const int h  = (blockIdx.x >> 4) & 15;
  const int b  = blockIdx.x >> 8;
  const int n0 = nt * 64;
#pragma unroll
  for (int i = 0; i < 4; ++i) {
    const int idx = i * 256 + t;
    const int row = idx >> 4, c4 = (idx & 15) * 4;
    *(float4*)&S[row][c4] =
        *(const float4*)&V[(size_t)(b * N_ + n0 + row) * HE + h * 64 + c4];
  }
  __syncthreads();
  const int e = t >> 2, nch = (t & 3) * 16;
  short8 h0, h1, l0, l1;
#pragma unroll
  for (int j = 0; j < 8; ++j) {
    ushort hh, ll;
    bsplit(S[nch + j][e], hh, ll);
    h0[j] = (short)hh; l0[j] = (short)ll;
    bsplit(S[nch + 8 + j][e], hh, ll);
    h1[j] = (short)hh; l1[j] = (short)ll;
  }
  const size_t off = (size_t)((b * H_ + h) * 64 + e) * N_ + n0 + nch;
  *(short8*)(Vth + off)     = h0;
  *(short8*)(Vth + off + 8) = h1;
  *(short8*)(Vtl + off)     = l0;
  *(short8*)(Vtl + off + 8) = l1;
}

// ---------------------------------------------------------------------------
// bf16x3 split MFMA GEMM, fp32 A converted in-loop (verified fallback path).
// ---------------------------------------------------------------------------
template <bool ROWMASK, bool SPLITOUT>
__global__ __launch_bounds__(256) void gemm_split3_kernel(
    const float* __restrict__ A, const ushort* __restrict__ Bth,
    const ushort* __restrict__ Btl, const float* __restrict__ bias,
    const float* __restrict__ rowmask, float* __restrict__ C,
    ushort* __restrict__ Ch, ushort* __restrict__ Cl, int Kd, int Nc) {
  __shared__ ushort Ah[128][32];
  __shared__ ushort Al[128][32];
  __shared__ ushort Bh[128][32];
  __shared__ ushort Bl[128][32];

  const int t    = threadIdx.x;
  const int lane = t & 63;
  const int wv   = t >> 6;
  const int l15  = lane & 15;
  const int quad = lane >> 4;
  const int wm   = (wv & 1) * 64;
  const int wn   = (wv >> 1) * 64;
  const int row0 = blockIdx.y * 128;
  const int col0 = blockIdx.x * 128;

  const int arow = t >> 1;
  const int half = t & 1;
  const float* Ap = A + (size_t)(row0 + arow) * Kd + half * 16;

  const int bn  = (lane >> 2);
  const int bk8 = (lane & 3) * 8;
  const ushort* Bhp = Bth + (size_t)(col0 + wv * 32 + bn) * Kd + bk8;
  const ushort* Blp = Btl + (size_t)(col0 + wv * 32 + bn) * Kd + bk8;

  f32x4 acc[4][4];
#pragma unroll
  for (int i = 0; i < 4; ++i)
#pragma unroll
    for (int j = 0; j < 4; ++j) acc[i][j] = {0.f, 0.f, 0.f, 0.f};

  for (int k0 = 0; k0 < Kd; k0 += 32) {
    __syncthreads();
#pragma unroll
    for (int j = 0; j < 2; ++j) {
      const int n = wv * 32 + j * 16 + bn;
      gld16(Bhp + (size_t)j * 16 * Kd + k0, &Bh[n][bk8]);
      gld16(Blp + (size_t)j * 16 * Kd + k0, &Bl[n][bk8]);
    }
    float f[16];
#pragma unroll
    for (int i = 0; i < 4; ++i) {
      const float4 v = *(const float4*)(Ap + k0 + i * 4);
      f[i * 4 + 0] = v.x; f[i * 4 + 1] = v.y;
      f[i * 4 + 2] = v.z; f[i * 4 + 3] = v.w;
    }
    ushort hh[16], ll[16];
#pragma unroll
    for (int i = 0; i < 16; ++i) bsplit(f[i], hh[i], ll[i]);
    uint4 wh0 = {pk(hh[0], hh[1]), pk(hh[2], hh[3]), pk(hh[4], hh[5]), pk(hh[6], hh[7])};
    uint4 wh1 = {pk(hh[8], hh[9]), pk(hh[10], hh[11]), pk(hh[12], hh[13]), pk(hh[14], hh[15])};
    uint4 wl0 = {pk(ll[0], ll[1]), pk(ll[2], ll[3]), pk(ll[4], ll[5]), pk(ll[6], ll[7])};
    uint4 wl1 = {pk(ll[8], ll[9]), pk(ll[10], ll[11]), pk(ll[12], ll[13]), pk(ll[14], ll[15])};
    *(uint4*)&Ah[arow][half * 16 + 0] = wh0;
    *(uint4*)&Ah[arow][half * 16 + 8] = wh1;
    *(uint4*)&Al[arow][half * 16 + 0] = wl0;
    *(uint4*)&Al[arow][half * 16 + 8] = wl1;

    __syncthreads();

    short8 ah[4], al[4], bh[4], bl[4];
#pragma unroll
    for (int mi = 0; mi < 4; ++mi) {
      ah[mi] = *(const short8*)&Ah[wm + mi * 16 + l15][quad * 8];
      al[mi] = *(const short8*)&Al[wm + mi * 16 + l15][quad * 8];
    }
#pragma unroll
    for (int ni = 0; ni < 4; ++ni) {
      bh[ni] = *(const short8*)&Bh[wn + ni * 16 + l15][quad * 8];
      bl[ni] = *(const short8*)&Bl[wn + ni * 16 + l15][quad * 8];
    }
#pragma unroll
    for (int mi = 0; mi < 4; ++mi)
#pragma unroll
      for (int ni = 0; ni < 4; ++ni) {
        acc[mi][ni] = __builtin_amdgcn_mfma_f32_16x16x32_bf16(
            ah[mi], bh[ni], acc[mi][ni], 0, 0, 0);
        acc[mi][ni] = __builtin_amdgcn_mfma_f32_16x16x32_bf16(
            ah[mi], bl[ni], acc[mi][ni], 0, 0, 0);
        acc[mi][ni] = __builtin_amdgcn_mfma_f32_16x16x32_bf16(
            al[mi], bh[ni], acc[mi][ni], 0, 0, 0);
      }
  }

  float bb[4];
#pragma unroll
  for (int ni = 0; ni < 4; ++ni) bb[ni] = bias[col0 + wn + ni * 16 + l15];
#pragma unroll
  for (int mi = 0; mi < 4; ++mi)
#pragma unroll
    for (int r = 0; r < 4; ++r) {
      const int row = row0 + wm + mi * 16 + quad * 4 + r;
      const float rm = ROWMASK ? rowmask[row] : 1.f;
#pragma unroll
      for (int ni = 0; ni < 4; ++ni) {
        const int col = col0 + wn + ni * 16 + l15;
        float v = acc[mi][ni][r] + bb[ni];
        if (SPLITOUT) {
          ushort vh, vl;
          bsplit(v, vh, vl);
          Ch[(size_t)row * Nc + col] = vh;
          Cl[(size_t)row * Nc + col] = vl;
        } else {
          if (ROWMASK) v *= rm;
          C[(size_t)row * Nc + col] = v;
        }
      }
    }
}

// ---------------------------------------------------------------------------
// R7: bf16x3 split MFMA GEMM, 256x128 tile, 4 waves (2x2), per-wave 128x64
// (8x4 fragment reuse -> 24 ds_read_b128 per 96 MFMAs = 0.25/MFMA vs 0.33
// at 64x64; R6 counters showed the 128^2 structure is LDS-read-count bound).
// Double-buffered LDS (96 KB) + R5-proven counted-vmcnt depth-2 sync
// (necessary now: 1 block/CU, no cross-block overlap). Chunk-XOR swizzle
// and XCD-aware remap retained (R4-verified).
// ---------------------------------------------------------------------------
#define STAGE_TILE(BUF, KK)                              \
  _Pragma("unroll")                                      \
  for (int j = 0; j < 4; ++j) {                          \
    const int rr = j * 64 + wv * 16;                     \
    const size_t o = (size_t)(j * 64) * Kd + (KK);       \
    gld16(Ahp + o, &Ah[BUF][rr][0]);                     \
    gld16(Alp + o, &Al[BUF][rr][0]);                     \
  }                                                      \
  _Pragma("unroll")                                      \
  for (int j = 0; j < 2; ++j) {                          \
    const int rr = j * 64 + wv * 16;                     \
    const size_t o = (size_t)(j * 64) * Kd + (KK);       \
    gld16(Bhp + o, &Bh[BUF][rr][0]);                     \
    gld16(Blp + o, &Bl[BUF][rr][0]);                     \
  }

#define COMPUTE_TILE(BUF)                                                    \
  {                                                                          \
    const int fo = ((quad ^ (l15 & 3)) << 3);                                \
    short8 bh[4], bl[4];                                                     \
    _Pragma("unroll")                                                        \
    for (int ni = 0; ni < 4; ++ni) {                                         \
      const int rb = wc64 + ni * 16 + l15;                                   \
      bh[ni] = *(const short8*)&Bh[BUF][rb][fo];                             \
      bl[ni] = *(const short8*)&Bl[BUF][rb][fo];                             \
    }                                                                        \
    __builtin_amdgcn_s_setprio(1);                                           \
    _Pragma("unroll")                                                        \
    for (int mi = 0; mi < 8; ++mi) {                                         \
      const int ra = wr128 + mi * 16 + l15;                                  \
      const short8 ah = *(const short8*)&Ah[BUF][ra][fo];                    \
      const short8 al = *(const short8*)&Al[BUF][ra][fo];                    \
      _Pragma("unroll")                                                      \
      for (int ni = 0; ni < 4; ++ni) {                                       \
        acc[mi][ni] = __builtin_amdgcn_mfma_f32_16x16x32_bf16(               \
            ah, bh[ni], acc[mi][ni], 0, 0, 0);                               \
        acc[mi][ni] = __builtin_amdgcn_mfma_f32_16x16x32_bf16(               \
            ah, bl[ni], acc[mi][ni], 0, 0, 0);                               \
        acc[mi][ni] = __builtin_amdgcn_mfma_f32_16x16x32_bf16(               \
            al, bh[ni], acc[mi][ni], 0, 0, 0);                               \
      }                                                                      \
    }                                                                        \
    __builtin_amdgcn_s_setprio(0);                                           \
  }

template <bool ROWMASK, bool SPLITOUT>
__global__ __launch_bounds__(256) void gemm_big_kernel(
    const ushort* __restrict__ Ath, const ushort* __restrict__ Atl,
    const ushort* __restrict__ Bth, const ushort* __restrict__ Btl,
    const float* __restrict__ bias, const float* __restrict__ rowmask,
    float* __restrict__ C, ushort* __restrict__ Ch, ushort* __restrict__ Cl,
    int Kd, int Nc, int gx) {
  __shared__ ushort Ah[2][256][32];   // 32 KB
  __shared__ ushort Al[2][256][32];   // 32 KB
  __shared__ ushort Bh[2][128][32];   // 16 KB
  __shared__ ushort Bl[2][128][32];   // 16 KB -> 96 KB total, 1 block/CU

  const int t    = threadIdx.x;
  const int lane = t & 63;
  const int wv   = t >> 6;
  const int l15  = lane & 15;
  const int quad = lane >> 4;
  const int wr128 = (wv >> 1) * 128;  // wave row base within 256
  const int wc64  = (wv & 1) * 64;    // wave col base within 128

  // XCD-aware decode: lin = (yb%8) + 8*xb + 8*gx*(yb/8)  (bijective, gy%8==0)
  const int lin  = blockIdx.x;
  const int xb   = (lin >> 3) % gx;
  const int yb   = (lin & 7) + 8 * ((lin >> 3) / gx);
  const int row0 = yb * 256;
  const int col0 = xb * 128;

  // staging: one gld16 covers 16 rows x 64B; lane -> (row lane>>2, chunk lane&3)
  // source chunk inverse-swizzled: (lane&3) ^ ((lane>>2)&3)
  const int srow = lane >> 2;
  const int sch8 = ((lane & 3) ^ (srow & 3)) * 8;
  const ushort* Ahp = Ath + (size_t)(row0 + wv * 16 + srow) * Kd + sch8;
  const ushort* Alp = Atl + (size_t)(row0 + wv * 16 + srow) * Kd + sch8;
  const ushort* Bhp = Bth + (size_t)(col0 + wv * 16 + srow) * Kd + sch8;
  const ushort* Blp = Btl + (size_t)(col0 + wv * 16 + srow) * Kd + sch8;

  f32x4 acc[8][4];
#pragma unroll
  for (int i = 0; i < 8; ++i)
#pragma unroll
    for (int j = 0; j < 4; ++j) acc[i][j] = {0.f, 0.f, 0.f, 0.f};

  // prologue: stage tile 0 into buffer 0 (12 gld16 per thread)
  STAGE_TILE(0, 0);

  int cur = 0;
  for (int k0 = 0; k0 < Kd; k0 += 32) {
    if (k0 + 32 < Kd) {
      const int nb = cur ^ 1;
      STAGE_TILE(nb, k0 + 32);
      // wait only for the PREVIOUS tile's 12 loads (issued a full iteration
      // ago); the 12 just issued stay in flight across the compute phase.
      asm volatile("s_waitcnt vmcnt(12)" ::: "memory");
    } else {
      asm volatile("s_waitcnt vmcnt(0)" ::: "memory");
    }
    __builtin_amdgcn_sched_barrier(0);
    __builtin_amdgcn_s_barrier();
    __builtin_amdgcn_sched_barrier(0);

    COMPUTE_TILE(cur);

    __builtin_amdgcn_sched_barrier(0);
    asm volatile("s_waitcnt lgkmcnt(0)" ::: "memory");
    __builtin_amdgcn_s_barrier();
    __builtin_amdgcn_sched_barrier(0);
    cur ^= 1;
  }

  float bb[4];
#pragma unroll
  for (int ni = 0; ni < 4; ++ni) bb[ni] = bias[col0 + wc64 + ni * 16 + l15];
#pragma unroll
  for (int mi = 0; mi < 8; ++mi)
#pragma unroll
    for (int r = 0; r < 4; ++r) {
      const int row = row0 + wr128 + mi * 16 + quad * 4 + r;
      const float rm = ROWMASK ? rowmask[row] : 1.f;
#pragma unroll
      for (int ni = 0; ni < 4; ++ni) {
        const int col = col0 + wc64 + ni * 16 + l15;
        float v = acc[mi][ni][r] + bb[ni];
        if (SPLITOUT) {
          ushort vh, vl;
          bsplit(v, vh, vl);
          Ch[(size_t)row * Nc + col] = vh;
          Cl[(size_t)row * Nc + col] = vl;
        } else {
          if (ROWMASK) v *= rm;
          C[(size_t)row * Nc + col] = v;
        }
      }
    }
}

#undef STAGE_TILE
#undef COMPUTE_TILE

// ---------------------------------------------------------------------------
// MFMA flash attention. Block = (b, h, 64 q-rows); 4 waves x 16 rows.
// ---------------------------------------------------------------------------
__global__ __launch_bounds__(256) void attn_mfma_kernel(
    const ushort* __restrict__ Qh, const ushort* __restrict__ Ql,
    const ushort* __restrict__ Kh, const ushort* __restrict__ Kl,
    const ushort* __restrict__ Vth, const ushort* __restrict__ Vtl,
    const unsigned char* __restrict__ kvmask, const float* __restrict__ tsmask,
    float* __restrict__ outv, float* __restrict__ scores_out) {
  __shared__ __align__(16) ushort sm[24576];  // 48 KB
  ushort* KHT = sm;            // [64 rows(n)][64 e] swizzled
  ushort* KLT = sm + 4096;
  ushort* VTH = sm + 8192;     // [64 rows(e)][64 n] swizzled
  ushort* VTL = sm + 12288;
  ushort* QHT = sm + 16384;    // [64 rows(m)][64 e] swizzled (dead after frag read)
  ushort* QLT = sm + 20480;

  const int t = threadIdx.x, lane = t & 63, wv = t >> 6;
  const int l15 = lane & 15, quad = lane >> 4;
  const int blk = blockIdx.x;          // b*128 + h*8 + mt
  const int mt = blk & 7;
  const int h  = (blk >> 3) & 15;
  const int b  = blk >> 7;
  const int m0 = mt * 64;
  const int lrow = lane >> 3, lch = lane & 7;
  const int gch8 = (lch ^ (lrow & 7)) * 8;  // swizzled 16B-chunk, ushort offset

  // ---- stage Q tile (wave wv: rows wv*16..+15), hi and lo ----
#pragma unroll
  for (int i = 0; i < 2; ++i) {
    const int rr = wv * 16 + i * 8;   // wave-uniform LDS row base
    const size_t g = (size_t)(b * M_ + m0 + rr + lrow) * HE + h * 64 + gch8;
    gld16(Qh + g, &QHT[rr * 64]);
    gld16(Ql + g, &QLT[rr * 64]);
  }
  __syncthreads();

  short8 qh[2], ql[2];
#pragma unroll
  for (int ks = 0; ks < 2; ++ks) {
    const int row = wv * 16 + l15;
    const int off = row * 64 + (((ks * 4 + quad) ^ (row & 7)) << 3);
    qh[ks] = *(const short8*)&QHT[off];
    ql[ks] = *(const short8*)&QLT[off];
  }
  __builtin_amdgcn_s_waitcnt(0);  // Q frag reads complete before Pu aliases region

  uint* Pu = (uint*)(sm + 16384) + wv * 1024;  // per-wave P, packed hi|lo

  float tsm_v[4];
#pragma unroll
  for (int r = 0; r < 4; ++r)
    tsm_v[r] = tsmask[b * M_ + m0 + wv * 16 + quad * 4 + r];

  float m_i[4] = {-INFINITY, -INFINITY, -INFINITY, -INFINITY};
  float l_i[4] = {0.f, 0.f, 0.f, 0.f};
  f32x4 acc[4];
#pragma unroll
  for (int es = 0; es < 4; ++es) acc[es] = {0.f, 0.f, 0.f, 0.f};

  for (int nc = 0; nc < 16; ++nc) {
    const int n0 = nc * 64;
    __syncthreads();  // prev iter's LDS reads done (iter0: Q frag reads done)
    // ---- stage K rows / V^T rows (wave wv: rows wv*16..+15 of each) ----
#pragma unroll
    for (int i = 0; i < 2; ++i) {
      const int rr = wv * 16 + i * 8;
      const size_t gk = (size_t)(b * N_ + n0 + rr + lrow) * HE + h * 64 + gch8;
      const size_t gv = (size_t)((b * H_ + h) * 64 + rr + lrow) * N_ + n0 + gch8;
      gld16(Kh + gk, &KHT[rr * 64]);
      gld16(Kl + gk, &KLT[rr * 64]);
      gld16(Vth + gv, &VTH[rr * 64]);
      gld16(Vtl + gv, &VTL[rr * 64]);
    }
    __syncthreads();  // drains vmcnt

    // ---- S = Q K^T (split3) ----
    f32x4 s[4];
#pragma unroll
    for (int ns = 0; ns < 4; ++ns) {
      s[ns] = {0.f, 0.f, 0.f, 0.f};
#pragma unroll
      for (int ks = 0; ks < 2; ++ks) {
        const int row = ns * 16 + l15;
        const int off = row * 64 + (((ks * 4 + quad) ^ (row & 7)) << 3);
        const short8 kh = *(const short8*)&KHT[off];
        const short8 kl = *(const short8*)&KLT[off];
        s[ns] = __builtin_amdgcn_mfma_f32_16x16x32_bf16(qh[ks], kh, s[ns], 0, 0, 0);
        s[ns] = __builtin_amdgcn_mfma_f32_16x16x32_bf16(qh[ks], kl, s[ns], 0, 0, 0);
        s[ns] = __builtin_amdgcn_mfma_f32_16x16x32_bf16(ql[ks], kh, s[ns], 0, 0, 0);
      }
    }

    // ---- scale + mask ----
    bool km[4];
#pragma unroll
    for (int ns = 0; ns < 4; ++ns)
      km[ns] = kvmask[b * N_ + n0 + ns * 16 + l15] != 0;
    float sc[4][4];  // [reg r][ns]
#pragma unroll
    for (int ns = 0; ns < 4; ++ns)
#pragma unroll
      for (int r = 0; r < 4; ++r)
        sc[r][ns] = km[ns] ? -INFINITY : s[ns][r] * 0.125f;

    // ---- scores_for_log ----
#pragma unroll
    for (int r = 0; r < 4; ++r) {
      const size_t base =
          ((size_t)(b * H_ + h) * M_ + m0 + wv * 16 + quad * 4 + r) * N_ + n0;
      const bool vr = tsm_v[r] != 0.f;
#pragma unroll
      for (int ns = 0; ns < 4; ++ns)
        scores_out[base + ns * 16 + l15] =
            (vr && !km[ns]) ? sc[r][ns] : NEG_BIG;
    }

    // ---- online softmax + P pack to LDS ----
#pragma unroll
    for (int r = 0; r < 4; ++r) {
      float cm = fmaxf(fmaxf(sc[r][0], sc[r][1]), fmaxf(sc[r][2], sc[r][3]));
#pragma unroll
      for (int o = 1; o < 16; o <<= 1) cm = fmaxf(cm, __shfl_xor(cm, o));
      const float nm = fmaxf(m_i[r], cm);
      const float alpha = (m_i[r] == -INFINITY) ? 0.f : __expf(m_i[r] - nm);
      float ps = 0.f;
      const int pr = quad * 4 + r;
#pragma unroll
      for (int ns = 0; ns < 4; ++ns) {
        const float p = (sc[r][ns] == -INFINITY) ? 0.f : __expf(sc[r][ns] - nm);
        ps += p;
        ushort ph_, pl_;
        bsplit(p, ph_, pl_);
        const int c = ns * 16 + l15;
        Pu[pr * 64 + (((c >> 2) ^ (pr & 7)) << 2) + (c & 3)] = pk(ph_, pl_);
      }
#pragma unroll
      for (int o = 1; o < 16; o <<= 1) ps += __shfl_xor(ps, o);
      l_i[r] = l_i[r] * alpha + ps;
      m_i[r] = nm;
#pragma unroll
      for (int es = 0; es < 4; ++es) acc[es][r] *= alpha;
    }

    // ---- PV (split3); P A-frag from packed LDS, V^T B-frag ----
#pragma unroll
    for (int ks = 0; ks < 2; ++ks) {
      const int c0 = ks * 8 + quad * 2;
      const uint* pb = &Pu[l15 * 64];
      const uint4 u0 = *(const uint4*)&pb[(c0 ^ (l15 & 7)) << 2];
      const uint4 u1 = *(const uint4*)&pb[((c0 + 1) ^ (l15 & 7)) << 2];
      short8 ph, pl;
      const uint* up0 = (const uint*)&u0;
      const uint* up1 = (const uint*)&u1;
#pragma unroll
      for (int j = 0; j < 4; ++j) {
        ph[j] = (short)(up0[j] & 0xffffu); pl[j] = (short)(up0[j] >> 16);
        ph[4 + j] = (short)(up1[j] & 0xffffu); pl[4 + j] = (short)(up1[j] >> 16);
      }
#pragma unroll
      for (int es = 0; es < 4; ++es) {
        const int row = es * 16 + l15;
        const int off = row * 64 + (((ks * 4 + quad) ^ (row & 7)) << 3);
        const short8 vh = *(const short8*)&VTH[off];
        const short8 vl = *(const short8*)&VTL[off];
        acc[es] = __builtin_amdgcn_mfma_f32_16x16x32_bf16(ph, vh, acc[es], 0, 0, 0);
        acc[es] = __builtin_amdgcn_mfma_f32_16x16x32_bf16(ph, vl, acc[es], 0, 0, 0);
        acc[es] = __builtin_amdgcn_mfma_f32_16x16x32_bf16(pl, vh, acc[es], 0, 0, 0);
      }
    }
  }

  // ---- epilogue: out_v = acc / l ----
#pragma unroll
  for (int r = 0; r < 4; ++r) {
    const float inv = (l_i[r] > 0.f) ? 1.f / l_i[r] : 0.f;
    const int grow = b * M_ + m0 + wv * 16 + quad * 4 + r;
#pragma unroll
    for (int es = 0; es < 4; ++es)
      outv[(size_t)grow * HE + h * 64 + es * 16 + l15] = acc[es][r] * inv;
  }
}

// ---------------------------------------------------------------------------
extern "C" void kernel_launch(void* const* d_in, const int* in_sizes, int n_in,
                              void* d_out, int out_size, void* d_ws,
                              size_t ws_size, hipStream_t stream) {
  const float* ts  = (const float*)d_in[0];
  const float* kv  = (const float*)d_in[1];
  const float* tsm = (const float*)d_in[2];
  const unsigned char* kvm = (const unsigned char*)d_in[3];
  const float* Wq = (const float*)d_in[4];
  const float* bq = (const float*)d_in[5];
  const float* Wk = (const float*)d_in[6];
  const float* bk = (const float*)d_in[7];
  const float* Wv = (const float*)d_in[8];
  const float* bv = (const float*)d_in[9];
  const float* Wo = (const float*)d_in[10];
  const float* bo = (const float*)d_in[11];

  float* out        = (float*)d_out;
  float* scores_out = out + (size_t)B_ * M_ * DLLM;

  char* ws = (char*)d_ws;
  constexpr size_t MB = 1024 * 1024;

  if (ws_size >= 260 * MB) {
    // ---------- pre-split path (A operands staged as bf16 hi/lo) ----------
    ushort* Kvh  = (ushort*)(ws);
    ushort* Kvl  = (ushort*)(ws + 64 * MB);
    float*  Vf   = (float*)(ws + 128 * MB);
    ushort* Khp  = (ushort*)(ws + 160 * MB);
    ushort* Klp  = (ushort*)(ws + 176 * MB);
    ushort* Qhp  = (ushort*)(ws + 192 * MB);
    ushort* Qlp  = (ushort*)(ws + 200 * MB);
    ushort* Tsh  = (ushort*)(ws + 208 * MB);
    ushort* Tsl  = (ushort*)(ws + 216 * MB);
    ushort* Wqh  = (ushort*)(ws + 224 * MB);
    ushort* Wql  = (ushort*)(ws + 226 * MB);
    ushort* Wkh  = (ushort*)(ws + 228 * MB);
    ushort* Wkl  = (ushort*)(ws + 236 * MB);
    ushort* Wvh  = (ushort*)(ws + 244 * MB);
    ushort* Wvl  = (ushort*)(ws + 252 * MB);
    // aliases valid once predecessors are dead (stream-ordered)
    ushort* Vthp  = (ushort*)(ws);
    ushort* Vtlp  = (ushort*)(ws + 16 * MB);
    ushort* outvh = (ushort*)(ws + 32 * MB);
    ushort* outvl = (ushort*)(ws + 40 * MB);
    ushort* Woh   = (ushort*)(ws + 64 * MB);
    ushort* Wol   = (ushort*)(ws + 72 * MB);
    float*  outv  = (float*)(ws + 128 * MB);

    // input pre-splits
    {
      const int n8_ts = (B_ * M_ * DTS) / 8;     // 512K
      asplit_kernel<<<dim3(n8_ts / 256), 256, 0, stream>>>(ts, Tsh, Tsl, n8_ts);
      const int n8_kv = (B_ * N_ * DLLM) / 8;    // 4M
      asplit_kernel<<<dim3(n8_kv / 256), 256, 0, stream>>>(kv, Kvh, Kvl, n8_kv);
    }

    // weight transpose+split
    tsplit_kernel<<<dim3(HE / 32, DTS / 32), 256, 0, stream>>>(Wq, Wqh, Wql, DTS, HE);
    tsplit_kernel<<<dim3(HE / 32, DLLM / 32), 256, 0, stream>>>(Wk, Wkh, Wkl, DLLM, HE);
    tsplit_kernel<<<dim3(HE / 32, DLLM / 32), 256, 0, stream>>>(Wv, Wvh, Wvl, DLLM, HE);

    // projections; 256x128 tiles, 1D grid, XCD-aware decode
    gemm_big_kernel<false, true><<<dim3((HE / 128) * ((B_ * M_) / 256)), 256, 0, stream>>>(
        Tsh, Tsl, Wqh, Wql, bq, nullptr, nullptr, Qhp, Qlp, DTS, HE, HE / 128);
    gemm_big_kernel<false, true><<<dim3((HE / 128) * ((B_ * N_) / 256)), 256, 0, stream>>>(
        Kvh, Kvl, Wkh, Wkl, bk, nullptr, nullptr, Khp, Klp, DLLM, HE, HE / 128);
    gemm_big_kernel<false, false><<<dim3((HE / 128) * ((B_ * N_) / 256)), 256, 0, stream>>>(
        Kvh, Kvl, Wvh, Wvl, bv, nullptr, Vf, nullptr, nullptr, DLLM, HE, HE / 128);

    // V^T split prep (Kv regions dead now; writes into [0,32))
    vtprep_kernel<<<dim3(B_ * H_ * 16), 256, 0, stream>>>(Vf, Vthp, Vtlp);

    // MFMA flash attention (+ scores_for_log); writes outv fp32 over dead Vf
    attn_mfma_kernel<<<dim3(B_ * H_ * (M_ / 64)), 256, 0, stream>>>(
        Qhp, Qlp, Khp, Klp, Vthp, Vtlp, kvm, tsm, outv, scores_out);

    // split attn output for pre-split O-GEMM
    {
      const int n8_o = (B_ * M_ * HE) / 8;       // 512K
      asplit_kernel<<<dim3(n8_o / 256), 256, 0, stream>>>(outv, outvh, outvl, n8_o);
    }

    // output projection
    tsplit_kernel<<<dim3(DLLM / 32, HE / 32), 256, 0, stream>>>(Wo, Woh, Wol, HE, DLLM);
    gemm_big_kernel<true, false><<<dim3((DLLM / 128) * ((B_ * M_) / 256)), 256, 0, stream>>>(
        outvh, outvl, Woh, Wol, bo, tsm, out, nullptr, nullptr, HE, DLLM, DLLM / 128);
  } else {
    // ---------- fallback: exact verified baseline path (116 MB) ----------
    float*  Vf   = (float*)(ws);
    float*  outv = (float*)(ws);
    ushort* Qhp  = (ushort*)(ws + 32 * MB);
    ushort* Qlp  = (ushort*)(ws + 40 * MB);
    ushort* Khp  = (ushort*)(ws + 48 * MB);
    ushort* Klp  = (ushort*)(ws + 64 * MB);
    ushort* Wqh  = (ushort*)(ws + 80 * MB);
    ushort* Wql  = (ushort*)(ws + 82 * MB);
    ushort* Wkh  = (ushort*)(ws + 84 * MB);
    ushort* Wkl  = (ushort*)(ws + 92 * MB);
    ushort* Wvh  = (ushort*)(ws + 100 * MB);
    ushort* Wvl  = (ushort*)(ws + 108 * MB);
    ushort* Vthp = (ushort*)(ws + 84 * MB);
    ushort* Vtlp = (ushort*)(ws + 100 * MB);
    ushort* Woh  = (ushort*)(ws + 48 * MB);
    ushort* Wol  = (ushort*)(ws + 56 * MB);

    tsplit_kernel<<<dim3(HE / 32, DTS / 32), 256, 0, stream>>>(Wq, Wqh, Wql, DTS, HE);
    tsplit_kernel<<<dim3(HE / 32, DLLM / 32), 256, 0, stream>>>(Wk, Wkh, Wkl, DLLM, HE);
    tsplit_kernel<<<dim3(HE / 32, DLLM / 32), 256, 0, stream>>>(Wv, Wvh, Wvl, DLLM, HE);

    gemm_split3_kernel<false, true><<<dim3(HE / 128, (B_ * M_) / 128), 256, 0, stream>>>(
        ts, Wqh, Wql, bq, nullptr, nullptr, Qhp, Qlp, DTS, HE);
    gemm_split3_kernel<false, true><<<dim3(HE / 128, (B_ * N_) / 128), 256, 0, stream>>>(
        kv, Wkh, Wkl, bk, nullptr, nullptr, Khp, Klp, DLLM, HE);
    gemm_split3_kernel<false, false><<<dim3(HE / 128, (B_ * N_) / 128), 256, 0, stream>>>(
        kv, Wvh, Wvl, bv, nullptr, Vf, nullptr, nullptr, DLLM, HE);

    vtprep_kernel<<<dim3(B_ * H_ * 16), 256, 0, stream>>>(Vf, Vthp, Vtlp);

    attn_mfma_kernel<<<dim3(B_ * H_ * (M_ / 64)), 256, 0, stream>>>(
        Qhp, Qlp, Khp, Klp, Vthp, Vtlp, kvm, tsm, outv, scores_out);

    tsplit_kernel<<<dim3(DLLM / 32, HE / 32), 256, 0, stream>>>(Wo, Woh, Wol, HE, DLLM);
    gemm_split3_kernel<true, false><<<dim3(DLLM / 128, (B_ * M_) / 128), 256, 0, stream>>>(
        outv, Woh, Wol, bo, tsm, out, nullptr, nullptr, HE, DLLM);
  }
}

// Round 8
// 1343.469 us; speedup vs baseline: 1.0905x; 1.0481x over previous
//
#include <hip/hip_runtime.h>
#include <math.h>

// Problem constants (match reference)
namespace {
constexpr int B_   = 8;
constexpr int M_   = 512;
constexpr int N_   = 1024;
constexpr int DTS  = 1024;
constexpr int DLLM = 4096;
constexpr int H_   = 16;
constexpr int E_   = 64;
constexpr int HE   = H_ * E_;   // 1024
// Finite stand-in for -inf in scores_for_log.
constexpr float NEG_BIG = -3.0e38f;
}

typedef __attribute__((ext_vector_type(4))) float f32x4;
typedef __attribute__((ext_vector_type(8))) short short8;
typedef unsigned int uint;
typedef unsigned short ushort;

// RNE split x = hi + lo (both representable as bf16; lo truncated).
__device__ inline void bsplit(float x, ushort& h, ushort& l) {
  uint u = __float_as_uint(x);
  uint hr = (u + 0x7FFFu + ((u >> 16) & 1u)) & 0xFFFF0000u;
  float lof = x - __uint_as_float(hr);
  h = (ushort)(hr >> 16);
  l = (ushort)(__float_as_uint(lof) >> 16);
}
__device__ inline uint pk(ushort a, ushort b) { return (uint)a | ((uint)b << 16); }

// async 16B global->LDS (m97-verified path)
__device__ inline void gld16(const void* g, void* l) {
  __builtin_amdgcn_global_load_lds(
      (const __attribute__((address_space(1))) uint*)g,
      (__attribute__((address_space(3))) uint*)l, 16, 0, 0);
}

// ---------------------------------------------------------------------------
// One-shot elementwise fp32 -> bf16 hi/lo split (row-major, no transpose).
// ---------------------------------------------------------------------------
__global__ __launch_bounds__(256) void asplit_kernel(
    const float* __restrict__ X, ushort* __restrict__ Xh,
    ushort* __restrict__ Xl, int n8) {
  const int idx = blockIdx.x * 256 + threadIdx.x;
  if (idx >= n8) return;
  const float4 a = *(const float4*)(X + (size_t)idx * 8);
  const float4 b = *(const float4*)(X + (size_t)idx * 8 + 4);
  float f[8] = {a.x, a.y, a.z, a.w, b.x, b.y, b.z, b.w};
  short8 h, l;
#pragma unroll
  for (int j = 0; j < 8; ++j) {
    ushort hh, ll;
    bsplit(f[j], hh, ll);
    h[j] = (short)hh;
    l[j] = (short)ll;
  }
  *(short8*)(Xh + (size_t)idx * 8) = h;
  *(short8*)(Xl + (size_t)idx * 8) = l;
}

// ---------------------------------------------------------------------------
// Weight transpose + bf16 split: W fp32 [K][N] -> Wth, Wtl bf16 [N][K].
// ---------------------------------------------------------------------------
__global__ __launch_bounds__(256) void tsplit_kernel(
    const float* __restrict__ W, ushort* __restrict__ Wth,
    ushort* __restrict__ Wtl, int K, int Nc) {
  __shared__ float S[32][33];
  const int t = threadIdx.x;
  const int n0 = blockIdx.x * 32, k0 = blockIdx.y * 32;
  const int c = t & 31, r8 = t >> 5;
#pragma unroll
  for (int i = 0; i < 4; ++i) {
    const int rr = r8 + i * 8;
    S[rr][c] = W[(size_t)(k0 + rr) * Nc + n0 + c];
  }
  __syncthreads();
#pragma unroll
  for (int i = 0; i < 4; ++i) {
    const int nn = r8 + i * 8;
    const float x = S[c][nn];
    ushort h, l;
    bsplit(x, h, l);
    const size_t o = (size_t)(n0 + nn) * K + k0 + c;
    Wth[o] = h;
    Wtl[o] = l;
  }
}

// ---------------------------------------------------------------------------
// V transpose prep: V fp32 [b*n][HE] -> Vth/Vtl bf16 [(b*H+h)*64+e][N].
// ---------------------------------------------------------------------------
__global__ __launch_bounds__(256) void vtprep_kernel(
    const float* __restrict__ V, ushort* __restrict__ Vth,
    ushort* __restrict__ Vtl) {
  __shared__ float S[64][68];
  const int t  = threadIdx.x;
  const int nt = blockIdx.x & 15;
  const int h  = (blockIdx.x >> 4) & 15;
  const int b  = blockIdx.x >> 8;
  const int n0 = nt * 64;
#pragma unroll
  for (int i = 0; i < 4; ++i) {
    const int idx = i * 256 + t;
    const int row = idx >> 4, c4 = (idx & 15) * 4;
    *(float4*)&S[row][c4] =
        *(const float4*)&V[(size_t)(b * N_ + n0 + row) * HE + h * 64 + c4];
  }
  __syncthreads();
  const int e = t >> 2, nch = (t & 3) * 16;
  short8 h0, h1, l0, l1;
#pragma unroll
  for (int j = 0; j < 8; ++j) {
    ushort hh, ll;
    bsplit(S[nch + j][e], hh, ll);
    h0[j] = (short)hh; l0[j] = (short)ll;
    bsplit(S[nch + 8 + j][e], hh, ll);
    h1[j] = (short)hh; l1[j] = (short)ll;
  }
  const size_t off = (size_t)((b * H_ + h) * 64 + e) * N_ + n0 + nch;
  *(short8*)(Vth + off)     = h0;
  *(short8*)(Vth + off + 8) = h1;
  *(short8*)(Vtl + off)     = l0;
  *(short8*)(Vtl + off + 8) = l1;
}

// ---------------------------------------------------------------------------
// bf16x3 split MFMA GEMM, fp32 A converted in-loop (verified fallback path).
// ---------------------------------------------------------------------------
template <bool ROWMASK, bool SPLITOUT>
__global__ __launch_bounds__(256) void gemm_split3_kernel(
    const float* __restrict__ A, const ushort* __restrict__ Bth,
    const ushort* __restrict__ Btl, const float* __restrict__ bias,
    const float* __restrict__ rowmask, float* __restrict__ C,
    ushort* __restrict__ Ch, ushort* __restrict__ Cl, int Kd, int Nc) {
  __shared__ ushort Ah[128][32];
  __shared__ ushort Al[128][32];
  __shared__ ushort Bh[128][32];
  __shared__ ushort Bl[128][32];

  const int t    = threadIdx.x;
  const int lane = t & 63;
  const int wv   = t >> 6;
  const int l15  = lane & 15;
  const int quad = lane >> 4;
  const int wm   = (wv & 1) * 64;
  const int wn   = (wv >> 1) * 64;
  const int row0 = blockIdx.y * 128;
  const int col0 = blockIdx.x * 128;

  const int arow = t >> 1;
  const int half = t & 1;
  const float* Ap = A + (size_t)(row0 + arow) * Kd + half * 16;

  const int bn  = (lane >> 2);
  const int bk8 = (lane & 3) * 8;
  const ushort* Bhp = Bth + (size_t)(col0 + wv * 32 + bn) * Kd + bk8;
  const ushort* Blp = Btl + (size_t)(col0 + wv * 32 + bn) * Kd + bk8;

  f32x4 acc[4][4];
#pragma unroll
  for (int i = 0; i < 4; ++i)
#pragma unroll
    for (int j = 0; j < 4; ++j) acc[i][j] = {0.f, 0.f, 0.f, 0.f};

  for (int k0 = 0; k0 < Kd; k0 += 32) {
    __syncthreads();
#pragma unroll
    for (int j = 0; j < 2; ++j) {
      const int n = wv * 32 + j * 16 + bn;
      gld16(Bhp + (size_t)j * 16 * Kd + k0, &Bh[n][bk8]);
      gld16(Blp + (size_t)j * 16 * Kd + k0, &Bl[n][bk8]);
    }
    float f[16];
#pragma unroll
    for (int i = 0; i < 4; ++i) {
      const float4 v = *(const float4*)(Ap + k0 + i * 4);
      f[i * 4 + 0] = v.x; f[i * 4 + 1] = v.y;
      f[i * 4 + 2] = v.z; f[i * 4 + 3] = v.w;
    }
    ushort hh[16], ll[16];
#pragma unroll
    for (int i = 0; i < 16; ++i) bsplit(f[i], hh[i], ll[i]);
    uint4 wh0 = {pk(hh[0], hh[1]), pk(hh[2], hh[3]), pk(hh[4], hh[5]), pk(hh[6], hh[7])};
    uint4 wh1 = {pk(hh[8], hh[9]), pk(hh[10], hh[11]), pk(hh[12], hh[13]), pk(hh[14], hh[15])};
    uint4 wl0 = {pk(ll[0], ll[1]), pk(ll[2], ll[3]), pk(ll[4], ll[5]), pk(ll[6], ll[7])};
    uint4 wl1 = {pk(ll[8], ll[9]), pk(ll[10], ll[11]), pk(ll[12], ll[13]), pk(ll[14], ll[15])};
    *(uint4*)&Ah[arow][half * 16 + 0] = wh0;
    *(uint4*)&Ah[arow][half * 16 + 8] = wh1;
    *(uint4*)&Al[arow][half * 16 + 0] = wl0;
    *(uint4*)&Al[arow][half * 16 + 8] = wl1;

    __syncthreads();

    short8 ah[4], al[4], bh[4], bl[4];
#pragma unroll
    for (int mi = 0; mi < 4; ++mi) {
      ah[mi] = *(const short8*)&Ah[wm + mi * 16 + l15][quad * 8];
      al[mi] = *(const short8*)&Al[wm + mi * 16 + l15][quad * 8];
    }
#pragma unroll
    for (int ni = 0; ni < 4; ++ni) {
      bh[ni] = *(const short8*)&Bh[wn + ni * 16 + l15][quad * 8];
      bl[ni] = *(const short8*)&Bl[wn + ni * 16 + l15][quad * 8];
    }
#pragma unroll
    for (int mi = 0; mi < 4; ++mi)
#pragma unroll
      for (int ni = 0; ni < 4; ++ni) {
        acc[mi][ni] = __builtin_amdgcn_mfma_f32_16x16x32_bf16(
            ah[mi], bh[ni], acc[mi][ni], 0, 0, 0);
        acc[mi][ni] = __builtin_amdgcn_mfma_f32_16x16x32_bf16(
            ah[mi], bl[ni], acc[mi][ni], 0, 0, 0);
        acc[mi][ni] = __builtin_amdgcn_mfma_f32_16x16x32_bf16(
            al[mi], bh[ni], acc[mi][ni], 0, 0, 0);
      }
  }

  float bb[4];
#pragma unroll
  for (int ni = 0; ni < 4; ++ni) bb[ni] = bias[col0 + wn + ni * 16 + l15];
#pragma unroll
  for (int mi = 0; mi < 4; ++mi)
#pragma unroll
    for (int r = 0; r < 4; ++r) {
      const int row = row0 + wm + mi * 16 + quad * 4 + r;
      const float rm = ROWMASK ? rowmask[row] : 1.f;
#pragma unroll
      for (int ni = 0; ni < 4; ++ni) {
        const int col = col0 + wn + ni * 16 + l15;
        float v = acc[mi][ni][r] + bb[ni];
        if (SPLITOUT) {
          ushort vh, vl;
          bsplit(v, vh, vl);
          Ch[(size_t)row * Nc + col] = vh;
          Cl[(size_t)row * Nc + col] = vl;
        } else {
          if (ROWMASK) v *= rm;
          C[(size_t)row * Nc + col] = v;
        }
      }
    }
}

// ---------------------------------------------------------------------------
// bf16x3 split MFMA GEMM, BOTH operands pre-split bf16 hi/lo (R4-verified
// structure: single-buffer, two __syncthreads per K-step, XCD-aware remap).
// ---------------------------------------------------------------------------
template <bool ROWMASK, bool SPLITOUT>
__global__ __launch_bounds__(256) void gemm_bb_kernel(
    const ushort* __restrict__ Ath, const ushort* __restrict__ Atl,
    const ushort* __restrict__ Bth, const ushort* __restrict__ Btl,
    const float* __restrict__ bias, const float* __restrict__ rowmask,
    float* __restrict__ C, ushort* __restrict__ Ch, ushort* __restrict__ Cl,
    int Kd, int Nc, int gx) {
  __shared__ ushort Ah[128][32];
  __shared__ ushort Al[128][32];
  __shared__ ushort Bh[128][32];
  __shared__ ushort Bl[128][32];

  const int t    = threadIdx.x;
  const int lane = t & 63;
  const int wv   = t >> 6;
  const int l15  = lane & 15;
  const int quad = lane >> 4;
  const int wm   = (wv & 1) * 64;
  const int wn   = (wv >> 1) * 64;

  // XCD-aware decode: lin = (yb%8) + 8*xb + 8*gx*(yb/8)  (bijective)
  const int lin  = blockIdx.x;
  const int xb   = (lin >> 3) % gx;
  const int yb   = (lin & 7) + 8 * ((lin >> 3) / gx);
  const int row0 = yb * 128;
  const int col0 = xb * 128;

  // per-lane source for 16B async staging (lane l -> LDS base + l*16B)
  const int rn  = (lane >> 2);
  const int rk8 = (lane & 3) * 8;
  const ushort* Ahp = Ath + (size_t)(row0 + wv * 32 + rn) * Kd + rk8;
  const ushort* Alp = Atl + (size_t)(row0 + wv * 32 + rn) * Kd + rk8;
  const ushort* Bhp = Bth + (size_t)(col0 + wv * 32 + rn) * Kd + rk8;
  const ushort* Blp = Btl + (size_t)(col0 + wv * 32 + rn) * Kd + rk8;

  f32x4 acc[4][4];
#pragma unroll
  for (int i = 0; i < 4; ++i)
#pragma unroll
    for (int j = 0; j < 4; ++j) acc[i][j] = {0.f, 0.f, 0.f, 0.f};

  for (int k0 = 0; k0 < Kd; k0 += 32) {
    __syncthreads();
#pragma unroll
    for (int j = 0; j < 2; ++j) {
      const int rr = wv * 32 + j * 16;
      const size_t o = (size_t)j * 16 * Kd + k0;
      gld16(Ahp + o, &Ah[rr][0]);
      gld16(Alp + o, &Al[rr][0]);
      gld16(Bhp + o, &Bh[rr][0]);
      gld16(Blp + o, &Bl[rr][0]);
    }
    __syncthreads();  // drains vmcnt -> staged tiles visible

    short8 ah[4], al[4], bh[4], bl[4];
#pragma unroll
    for (int mi = 0; mi < 4; ++mi) {
      ah[mi] = *(const short8*)&Ah[wm + mi * 16 + l15][quad * 8];
      al[mi] = *(const short8*)&Al[wm + mi * 16 + l15][quad * 8];
    }
#pragma unroll
    for (int ni = 0; ni < 4; ++ni) {
      bh[ni] = *(const short8*)&Bh[wn + ni * 16 + l15][quad * 8];
      bl[ni] = *(const short8*)&Bl[wn + ni * 16 + l15][quad * 8];
    }
#pragma unroll
    for (int mi = 0; mi < 4; ++mi)
#pragma unroll
      for (int ni = 0; ni < 4; ++ni) {
        acc[mi][ni] = __builtin_amdgcn_mfma_f32_16x16x32_bf16(
            ah[mi], bh[ni], acc[mi][ni], 0, 0, 0);
        acc[mi][ni] = __builtin_amdgcn_mfma_f32_16x16x32_bf16(
            ah[mi], bl[ni], acc[mi][ni], 0, 0, 0);
        acc[mi][ni] = __builtin_amdgcn_mfma_f32_16x16x32_bf16(
            al[mi], bh[ni], acc[mi][ni], 0, 0, 0);
      }
  }

  float bb[4];
#pragma unroll
  for (int ni = 0; ni < 4; ++ni) bb[ni] = bias[col0 + wn + ni * 16 + l15];
#pragma unroll
  for (int mi = 0; mi < 4; ++mi)
#pragma unroll
    for (int r = 0; r < 4; ++r) {
      const int row = row0 + wm + mi * 16 + quad * 4 + r;
      const float rm = ROWMASK ? rowmask[row] : 1.f;
#pragma unroll
      for (int ni = 0; ni < 4; ++ni) {
        const int col = col0 + wn + ni * 16 + l15;
        float v = acc[mi][ni][r] + bb[ni];
        if (SPLITOUT) {
          ushort vh, vl;
          bsplit(v, vh, vl);
          Ch[(size_t)row * Nc + col] = vh;
          Cl[(size_t)row * Nc + col] = vl;
        } else {
          if (ROWMASK) v *= rm;
          C[(size_t)row * Nc + col] = v;
        }
      }
    }
}

// ---------------------------------------------------------------------------
// R8: FUSED K-proj + V-proj GEMM. Both read the same A (Kv hi/lo); A is
// staged ONCE and each A-fragment feeds 6 MFMAs (3 K-proj + 3 V-proj).
// LDS reads/wave/K-step: 8 A + 16 B = 24 for 96 MFMAs (0.25/MFMA vs 0.33
// in gemm_bb) -- attacks the measured LDS-read-throughput bound (R7 model:
// util = MFMA_cyc/LDS_cyc = 465/1280 = 36%, measured 37%). LDS 48 KB,
// grid 512 -> 2 blocks/CU kept (R7 lesson: losing occupancy costs more
// than LDS savings). Sync structure identical to R4 (every pipelining
// variant measured null). Outputs: K split bf16 hi/lo + V fp32.
// ---------------------------------------------------------------------------
__global__ __launch_bounds__(256) void gemm_bbkv_kernel(
    const ushort* __restrict__ Ath, const ushort* __restrict__ Atl,
    const ushort* __restrict__ Bkth, const ushort* __restrict__ Bktl,
    const ushort* __restrict__ Bvth, const ushort* __restrict__ Bvtl,
    const float* __restrict__ biask, const float* __restrict__ biasv,
    ushort* __restrict__ Ckh, ushort* __restrict__ Ckl,
    float* __restrict__ Cv, int Kd, int Nc, int gx) {
  __shared__ ushort Ah[128][32];
  __shared__ ushort Al[128][32];
  __shared__ ushort Bkh[128][32];
  __shared__ ushort Bkl[128][32];
  __shared__ ushort Bvh[128][32];
  __shared__ ushort Bvl[128][32];   // 48 KB total

  const int t    = threadIdx.x;
  const int lane = t & 63;
  const int wv   = t >> 6;
  const int l15  = lane & 15;
  const int quad = lane >> 4;
  const int wm   = (wv & 1) * 64;
  const int wn   = (wv >> 1) * 64;

  // XCD-aware decode (bijective; gy % 8 == 0 holds: 64)
  const int lin  = blockIdx.x;
  const int xb   = (lin >> 3) % gx;
  const int yb   = (lin & 7) + 8 * ((lin >> 3) / gx);
  const int row0 = yb * 128;
  const int col0 = xb * 128;

  const int rn  = (lane >> 2);
  const int rk8 = (lane & 3) * 8;
  const ushort* Ahp  = Ath  + (size_t)(row0 + wv * 32 + rn) * Kd + rk8;
  const ushort* Alp  = Atl  + (size_t)(row0 + wv * 32 + rn) * Kd + rk8;
  const ushort* Bkhp = Bkth + (size_t)(col0 + wv * 32 + rn) * Kd + rk8;
  const ushort* Bklp = Bktl + (size_t)(col0 + wv * 32 + rn) * Kd + rk8;
  const ushort* Bvhp = Bvth + (size_t)(col0 + wv * 32 + rn) * Kd + rk8;
  const ushort* Bvlp = Bvtl + (size_t)(col0 + wv * 32 + rn) * Kd + rk8;

  f32x4 acck[4][4], accv[4][4];
#pragma unroll
  for (int i = 0; i < 4; ++i)
#pragma unroll
    for (int j = 0; j < 4; ++j) {
      acck[i][j] = {0.f, 0.f, 0.f, 0.f};
      accv[i][j] = {0.f, 0.f, 0.f, 0.f};
    }

  for (int k0 = 0; k0 < Kd; k0 += 32) {
    __syncthreads();
#pragma unroll
    for (int j = 0; j < 2; ++j) {
      const int rr = wv * 32 + j * 16;
      const size_t o = (size_t)j * 16 * Kd + k0;
      gld16(Ahp  + o, &Ah[rr][0]);
      gld16(Alp  + o, &Al[rr][0]);
      gld16(Bkhp + o, &Bkh[rr][0]);
      gld16(Bklp + o, &Bkl[rr][0]);
      gld16(Bvhp + o, &Bvh[rr][0]);
      gld16(Bvlp + o, &Bvl[rr][0]);
    }
    __syncthreads();  // drains vmcnt -> staged tiles visible

    short8 ah[4], al[4];
#pragma unroll
    for (int mi = 0; mi < 4; ++mi) {
      ah[mi] = *(const short8*)&Ah[wm + mi * 16 + l15][quad * 8];
      al[mi] = *(const short8*)&Al[wm + mi * 16 + l15][quad * 8];
    }
    // ni-outer: only one column's B fragments live at a time (VGPR control)
#pragma unroll
    for (int ni = 0; ni < 4; ++ni) {
      const int rb = wn + ni * 16 + l15;
      const short8 bkh = *(const short8*)&Bkh[rb][quad * 8];
      const short8 bkl = *(const short8*)&Bkl[rb][quad * 8];
      const short8 bvh = *(const short8*)&Bvh[rb][quad * 8];
      const short8 bvl = *(const short8*)&Bvl[rb][quad * 8];
#pragma unroll
      for (int mi = 0; mi < 4; ++mi) {
        acck[mi][ni] = __builtin_amdgcn_mfma_f32_16x16x32_bf16(
            ah[mi], bkh, acck[mi][ni], 0, 0, 0);
        acck[mi][ni] = __builtin_amdgcn_mfma_f32_16x16x32_bf16(
            ah[mi], bkl, acck[mi][ni], 0, 0, 0);
        acck[mi][ni] = __builtin_amdgcn_mfma_f32_16x16x32_bf16(
            al[mi], bkh, acck[mi][ni], 0, 0, 0);
        accv[mi][ni] = __builtin_amdgcn_mfma_f32_16x16x32_bf16(
            ah[mi], bvh, accv[mi][ni], 0, 0, 0);
        accv[mi][ni] = __builtin_amdgcn_mfma_f32_16x16x32_bf16(
            ah[mi], bvl, accv[mi][ni], 0, 0, 0);
        accv[mi][ni] = __builtin_amdgcn_mfma_f32_16x16x32_bf16(
            al[mi], bvh, accv[mi][ni], 0, 0, 0);
      }
    }
  }

  float bbk[4], bbv[4];
#pragma unroll
  for (int ni = 0; ni < 4; ++ni) {
    bbk[ni] = biask[col0 + wn + ni * 16 + l15];
    bbv[ni] = biasv[col0 + wn + ni * 16 + l15];
  }
#pragma unroll
  for (int mi = 0; mi < 4; ++mi)
#pragma unroll
    for (int r = 0; r < 4; ++r) {
      const int row = row0 + wm + mi * 16 + quad * 4 + r;
#pragma unroll
      for (int ni = 0; ni < 4; ++ni) {
        const int col = col0 + wn + ni * 16 + l15;
        const float vk = acck[mi][ni][r] + bbk[ni];
        ushort vh, vl;
        bsplit(vk, vh, vl);
        Ckh[(size_t)row * Nc + col] = vh;
        Ckl[(size_t)row * Nc + col] = vl;
        Cv[(size_t)row * Nc + col]  = accv[mi][ni][r] + bbv[ni];
      }
    }
}

// ---------------------------------------------------------------------------
// MFMA flash attention. Block = (b, h, 64 q-rows); 4 waves x 16 rows.
// ---------------------------------------------------------------------------
__global__ __launch_bounds__(256) void attn_mfma_kernel(
    const ushort* __restrict__ Qh, const ushort* __restrict__ Ql,
    const ushort* __restrict__ Kh, const ushort* __restrict__ Kl,
    const ushort* __restrict__ Vth, const ushort* __restrict__ Vtl,
    const unsigned char* __restrict__ kvmask, const float* __restrict__ tsmask,
    float* __restrict__ outv, float* __restrict__ scores_out) {
  __shared__ __align__(16) ushort sm[24576];  // 48 KB
  ushort* KHT = sm;            // [64 rows(n)][64 e] swizzled
  ushort* KLT = sm + 4096;
  ushort* VTH = sm + 8192;     // [64 rows(e)][64 n] swizzled
  ushort* VTL = sm + 12288;
  ushort* QHT = sm + 16384;    // [64 rows(m)][64 e] swizzled (dead after frag read)
  ushort* QLT = sm + 20480;

  const int t = threadIdx.x, lane = t & 63, wv = t >> 6;
  const int l15 = lane & 15, quad = lane >> 4;
  const int blk = blockIdx.x;          // b*128 + h*8 + mt
  const int mt = blk & 7;
  const int h  = (blk >> 3) & 15;
  const int b  = blk >> 7;
  const int m0 = mt * 64;
  const int lrow = lane >> 3, lch = lane & 7;
  const int gch8 = (lch ^ (lrow & 7)) * 8;  // swizzled 16B-chunk, ushort offset

  // ---- stage Q tile (wave wv: rows wv*16..+15), hi and lo ----
#pragma unroll
  for (int i = 0; i < 2; ++i) {
    const int rr = wv * 16 + i * 8;   // wave-uniform LDS row base
    const size_t g = (size_t)(b * M_ + m0 + rr + lrow) * HE + h * 64 + gch8;
    gld16(Qh + g, &QHT[rr * 64]);
    gld16(Ql + g, &QLT[rr * 64]);
  }
  __syncthreads();

  short8 qh[2], ql[2];
#pragma unroll
  for (int ks = 0; ks < 2; ++ks) {
    const int row = wv * 16 + l15;
    const int off = row * 64 + (((ks * 4 + quad) ^ (row & 7)) << 3);
    qh[ks] = *(const short8*)&QHT[off];
    ql[ks] = *(const short8*)&QLT[off];
  }
  __builtin_amdgcn_s_waitcnt(0);  // Q frag reads complete before Pu aliases region

  uint* Pu = (uint*)(sm + 16384) + wv * 1024;  // per-wave P, packed hi|lo

  float tsm_v[4];
#pragma unroll
  for (int r = 0; r < 4; ++r)
    tsm_v[r] = tsmask[b * M_ + m0 + wv * 16 + quad * 4 + r];

  float m_i[4] = {-INFINITY, -INFINITY, -INFINITY, -INFINITY};
  float l_i[4] = {0.f, 0.f, 0.f, 0.f};
  f32x4 acc[4];
#pragma unroll
  for (int es = 0; es < 4; ++es) acc[es] = {0.f, 0.f, 0.f, 0.f};

  for (int nc = 0; nc < 16; ++nc) {
    const int n0 = nc * 64;
    __syncthreads();  // prev iter's LDS reads done (iter0: Q frag reads done)
    // ---- stage K rows / V^T rows (wave wv: rows wv*16..+15 of each) ----
#pragma unroll
    for (int i = 0; i < 2; ++i) {
      const int rr = wv * 16 + i * 8;
      const size_t gk = (size_t)(b * N_ + n0 + rr + lrow) * HE + h * 64 + gch8;
      const size_t gv = (size_t)((b * H_ + h) * 64 + rr + lrow) * N_ + n0 + gch8;
      gld16(Kh + gk, &KHT[rr * 64]);
      gld16(Kl + gk, &KLT[rr * 64]);
      gld16(Vth + gv, &VTH[rr * 64]);
      gld16(Vtl + gv, &VTL[rr * 64]);
    }
    __syncthreads();  // drains vmcnt

    // ---- S = Q K^T (split3) ----
    f32x4 s[4];
#pragma unroll
    for (int ns = 0; ns < 4; ++ns) {
      s[ns] = {0.f, 0.f, 0.f, 0.f};
#pragma unroll
      for (int ks = 0; ks < 2; ++ks) {
        const int row = ns * 16 + l15;
        const int off = row * 64 + (((ks * 4 + quad) ^ (row & 7)) << 3);
        const short8 kh = *(const short8*)&KHT[off];
        const short8 kl = *(const short8*)&KLT[off];
        s[ns] = __builtin_amdgcn_mfma_f32_16x16x32_bf16(qh[ks], kh, s[ns], 0, 0, 0);
        s[ns] = __builtin_amdgcn_mfma_f32_16x16x32_bf16(qh[ks], kl, s[ns], 0, 0, 0);
        s[ns] = __builtin_amdgcn_mfma_f32_16x16x32_bf16(ql[ks], kh, s[ns], 0, 0, 0);
      }
    }

    // ---- scale + mask ----
    bool km[4];
#pragma unroll
    for (int ns = 0; ns < 4; ++ns)
      km[ns] = kvmask[b * N_ + n0 + ns * 16 + l15] != 0;
    float sc[4][4];  // [reg r][ns]
#pragma unroll
    for (int ns = 0; ns < 4; ++ns)
#pragma unroll
      for (int r = 0; r < 4; ++r)
        sc[r][ns] = km[ns] ? -INFINITY : s[ns][r] * 0.125f;

    // ---- scores_for_log ----
#pragma unroll
    for (int r = 0; r < 4; ++r) {
      const size_t base =
          ((size_t)(b * H_ + h) * M_ + m0 + wv * 16 + quad * 4 + r) * N_ + n0;
      const bool vr = tsm_v[r] != 0.f;
#pragma unroll
      for (int ns = 0; ns < 4; ++ns)
        scores_out[base + ns * 16 + l15] =
            (vr && !km[ns]) ? sc[r][ns] : NEG_BIG;
    }

    // ---- online softmax + P pack to LDS ----
#pragma unroll
    for (int r = 0; r < 4; ++r) {
      float cm = fmaxf(fmaxf(sc[r][0], sc[r][1]), fmaxf(sc[r][2], sc[r][3]));
#pragma unroll
      for (int o = 1; o < 16; o <<= 1) cm = fmaxf(cm, __shfl_xor(cm, o));
      const float nm = fmaxf(m_i[r], cm);
      const float alpha = (m_i[r] == -INFINITY) ? 0.f : __expf(m_i[r] - nm);
      float ps = 0.f;
      const int pr = quad * 4 + r;
#pragma unroll
      for (int ns = 0; ns < 4; ++ns) {
        const float p = (sc[r][ns] == -INFINITY) ? 0.f : __expf(sc[r][ns] - nm);
        ps += p;
        ushort ph_, pl_;
        bsplit(p, ph_, pl_);
        const int c = ns * 16 + l15;
        Pu[pr * 64 + (((c >> 2) ^ (pr & 7)) << 2) + (c & 3)] = pk(ph_, pl_);
      }
#pragma unroll
      for (int o = 1; o < 16; o <<= 1) ps += __shfl_xor(ps, o);
      l_i[r] = l_i[r] * alpha + ps;
      m_i[r] = nm;
#pragma unroll
      for (int es = 0; es < 4; ++es) acc[es][r] *= alpha;
    }

    // ---- PV (split3); P A-frag from packed LDS, V^T B-frag ----
#pragma unroll
    for (int ks = 0; ks < 2; ++ks) {
      const int c0 = ks * 8 + quad * 2;
      const uint* pb = &Pu[l15 * 64];
      const uint4 u0 = *(const uint4*)&pb[(c0 ^ (l15 & 7)) << 2];
      const uint4 u1 = *(const uint4*)&pb[((c0 + 1) ^ (l15 & 7)) << 2];
      short8 ph, pl;
      const uint* up0 = (const uint*)&u0;
      const uint* up1 = (const uint*)&u1;
#pragma unroll
      for (int j = 0; j < 4; ++j) {
        ph[j] = (short)(up0[j] & 0xffffu); pl[j] = (short)(up0[j] >> 16);
        ph[4 + j] = (short)(up1[j] & 0xffffu); pl[4 + j] = (short)(up1[j] >> 16);
      }
#pragma unroll
      for (int es = 0; es < 4; ++es) {
        const int row = es * 16 + l15;
        const int off = row * 64 + (((ks * 4 + quad) ^ (row & 7)) << 3);
        const short8 vh = *(const short8*)&VTH[off];
        const short8 vl = *(const short8*)&VTL[off];
        acc[es] = __builtin_amdgcn_mfma_f32_16x16x32_bf16(ph, vh, acc[es], 0, 0, 0);
        acc[es] = __builtin_amdgcn_mfma_f32_16x16x32_bf16(ph, vl, acc[es], 0, 0, 0);
        acc[es] = __builtin_amdgcn_mfma_f32_16x16x32_bf16(pl, vh, acc[es], 0, 0, 0);
      }
    }
  }

  // ---- epilogue: out_v = acc / l ----
#pragma unroll
  for (int r = 0; r < 4; ++r) {
    const float inv = (l_i[r] > 0.f) ? 1.f / l_i[r] : 0.f;
    const int grow = b * M_ + m0 + wv * 16 + quad * 4 + r;
#pragma unroll
    for (int es = 0; es < 4; ++es)
      outv[(size_t)grow * HE + h * 64 + es * 16 + l15] = acc[es][r] * inv;
  }
}

// ---------------------------------------------------------------------------
extern "C" void kernel_launch(void* const* d_in, const int* in_sizes, int n_in,
                              void* d_out, int out_size, void* d_ws,
                              size_t ws_size, hipStream_t stream) {
  const float* ts  = (const float*)d_in[0];
  const float* kv  = (const float*)d_in[1];
  const float* tsm = (const float*)d_in[2];
  const unsigned char* kvm = (const unsigned char*)d_in[3];
  const float* Wq = (const float*)d_in[4];
  const float* bq = (const float*)d_in[5];
  const float* Wk = (const float*)d_in[6];
  const float* bk = (const float*)d_in[7];
  const float* Wv = (const float*)d_in[8];
  const float* bv = (const float*)d_in[9];
  const float* Wo = (const float*)d_in[10];
  const float* bo = (const float*)d_in[11];

  float* out        = (float*)d_out;
  float* scores_out = out + (size_t)B_ * M_ * DLLM;

  char* ws = (char*)d_ws;
  constexpr size_t MB = 1024 * 1024;

  if (ws_size >= 260 * MB) {
    // ---------- pre-split path (A operands staged as bf16 hi/lo) ----------
    ushort* Kvh  = (ushort*)(ws);
    ushort* Kvl  = (ushort*)(ws + 64 * MB);
    float*  Vf   = (float*)(ws + 128 * MB);
    ushort* Khp  = (ushort*)(ws + 160 * MB);
    ushort* Klp  = (ushort*)(ws + 176 * MB);
    ushort* Qhp  = (ushort*)(ws + 192 * MB);
    ushort* Qlp  = (ushort*)(ws + 200 * MB);
    ushort* Tsh  = (ushort*)(ws + 208 * MB);
    ushort* Tsl  = (ushort*)(ws + 216 * MB);
    ushort* Wqh  = (ushort*)(ws + 224 * MB);
    ushort* Wql  = (ushort*)(ws + 226 * MB);
    ushort* Wkh  = (ushort*)(ws + 228 * MB);
    ushort* Wkl  = (ushort*)(ws + 236 * MB);
    ushort* Wvh  = (ushort*)(ws + 244 * MB);
    ushort* Wvl  = (ushort*)(ws + 252 * MB);
    // aliases valid once predecessors are dead (stream-ordered)
    ushort* Vthp  = (ushort*)(ws);
    ushort* Vtlp  = (ushort*)(ws + 16 * MB);
    ushort* outvh = (ushort*)(ws + 32 * MB);
    ushort* outvl = (ushort*)(ws + 40 * MB);
    ushort* Woh   = (ushort*)(ws + 64 * MB);
    ushort* Wol   = (ushort*)(ws + 72 * MB);
    float*  outv  = (float*)(ws + 128 * MB);

    // input pre-splits
    {
      const int n8_ts = (B_ * M_ * DTS) / 8;     // 512K
      asplit_kernel<<<dim3(n8_ts / 256), 256, 0, stream>>>(ts, Tsh, Tsl, n8_ts);
      const int n8_kv = (B_ * N_ * DLLM) / 8;    // 4M
      asplit_kernel<<<dim3(n8_kv / 256), 256, 0, stream>>>(kv, Kvh, Kvl, n8_kv);
    }

    // weight transpose+split
    tsplit_kernel<<<dim3(HE / 32, DTS / 32), 256, 0, stream>>>(Wq, Wqh, Wql, DTS, HE);
    tsplit_kernel<<<dim3(HE / 32, DLLM / 32), 256, 0, stream>>>(Wk, Wkh, Wkl, DLLM, HE);
    tsplit_kernel<<<dim3(HE / 32, DLLM / 32), 256, 0, stream>>>(Wv, Wvh, Wvl, DLLM, HE);

    // Q projection (R4-verified gemm_bb)
    gemm_bb_kernel<false, true><<<dim3((HE / 128) * ((B_ * M_) / 128)), 256, 0, stream>>>(
        Tsh, Tsl, Wqh, Wql, bq, nullptr, nullptr, Qhp, Qlp, DTS, HE, HE / 128);

    // FUSED K+V projection: A staged once, both outputs in one pass
    gemm_bbkv_kernel<<<dim3((HE / 128) * ((B_ * N_) / 128)), 256, 0, stream>>>(
        Kvh, Kvl, Wkh, Wkl, Wvh, Wvl, bk, bv, Khp, Klp, Vf, DLLM, HE, HE / 128);

    // V^T split prep (Kv regions dead now; writes into [0,32))
    vtprep_kernel<<<dim3(B_ * H_ * 16), 256, 0, stream>>>(Vf, Vthp, Vtlp);

    // MFMA flash attention (+ scores_for_log); writes outv fp32 over dead Vf
    attn_mfma_kernel<<<dim3(B_ * H_ * (M_ / 64)), 256, 0, stream>>>(
        Qhp, Qlp, Khp, Klp, Vthp, Vtlp, kvm, tsm, outv, scores_out);

    // split attn output for pre-split O-GEMM
    {
      const int n8_o = (B_ * M_ * HE) / 8;       // 512K
      asplit_kernel<<<dim3(n8_o / 256), 256, 0, stream>>>(outv, outvh, outvl, n8_o);
    }

    // output projection (R4-verified gemm_bb)
    tsplit_kernel<<<dim3(DLLM / 32, HE / 32), 256, 0, stream>>>(Wo, Woh, Wol, HE, DLLM);
    gemm_bb_kernel<true, false><<<dim3((DLLM / 128) * ((B_ * M_) / 128)), 256, 0, stream>>>(
        outvh, outvl, Woh, Wol, bo, tsm, out, nullptr, nullptr, HE, DLLM, DLLM / 128);
  } else {
    // ---------- fallback: exact verified baseline path (116 MB) ----------
    float*  Vf   = (float*)(ws);
    float*  outv = (float*)(ws);
    ushort* Qhp  = (ushort*)(ws + 32 * MB);
    ushort* Qlp  = (ushort*)(ws + 40 * MB);
    ushort* Khp  = (ushort*)(ws + 48 * MB);
    ushort* Klp  = (ushort*)(ws + 64 * MB);
    ushort* Wqh  = (ushort*)(ws + 80 * MB);
    ushort* Wql  = (ushort*)(ws + 82 * MB);
    ushort* Wkh  = (ushort*)(ws + 84 * MB);
    ushort* Wkl  = (ushort*)(ws + 92 * MB);
    ushort* Wvh  = (ushort*)(ws + 100 * MB);
    ushort* Wvl  = (ushort*)(ws + 108 * MB);
    ushort* Vthp = (ushort*)(ws + 84 * MB);
    ushort* Vtlp = (ushort*)(ws + 100 * MB);
    ushort* Woh  = (ushort*)(ws + 48 * MB);
    ushort* Wol  = (ushort*)(ws + 56 * MB);

    tsplit_kernel<<<dim3(HE / 32, DTS / 32), 256, 0, stream>>>(Wq, Wqh, Wql, DTS, HE);
    tsplit_kernel<<<dim3(HE / 32, DLLM / 32), 256, 0, stream>>>(Wk, Wkh, Wkl, DLLM, HE);
    tsplit_kernel<<<dim3(HE / 32, DLLM / 32), 256, 0, stream>>>(Wv, Wvh, Wvl, DLLM, HE);

    gemm_split3_kernel<false, true><<<dim3(HE / 128, (B_ * M_) / 128), 256, 0, stream>>>(
        ts, Wqh, Wql, bq, nullptr, nullptr, Qhp, Qlp, DTS, HE);
    gemm_split3_kernel<false, true><<<dim3(HE / 128, (B_ * N_) / 128), 256, 0, stream>>>(
        kv, Wkh, Wkl, bk, nullptr, nullptr, Khp, Klp, DLLM, HE);
    gemm_split3_kernel<false, false><<<dim3(HE / 128, (B_ * N_) / 128), 256, 0, stream>>>(
        kv, Wvh, Wvl, bv, nullptr, Vf, nullptr, nullptr, DLLM, HE);

    vtprep_kernel<<<dim3(B_ * H_ * 16), 256, 0, stream>>>(Vf, Vthp, Vtlp);

    attn_mfma_kernel<<<dim3(B_ * H_ * (M_ / 64)), 256, 0, stream>>>(
        Qhp, Qlp, Khp, Klp, Vthp, Vtlp, kvm, tsm, outv, scores_out);

    tsplit_kernel<<<dim3(DLLM / 32, HE / 32), 256, 0, stream>>>(Wo, Woh, Wol, HE, DLLM);
    gemm_split3_kernel<true, false><<<dim3(DLLM / 128, (B_ * M_) / 128), 256, 0, stream>>>(
        outv, Woh, Wol, bo, tsm, out, nullptr, nullptr, HE, DLLM);
  }
}

// Round 9
// 1274.886 us; speedup vs baseline: 1.1492x; 1.0538x over previous
//
#include <hip/hip_runtime.h>
#include <math.h>

// Problem constants (match reference)
namespace {
constexpr int B_   = 8;
constexpr int M_   = 512;
constexpr int N_   = 1024;
constexpr int DTS  = 1024;
constexpr int DLLM = 4096;
constexpr int H_   = 16;
constexpr int E_   = 64;
constexpr int HE   = H_ * E_;   // 1024
constexpr float NEG_BIG = -3.0e38f;
constexpr size_t PST = (size_t)8192 * 1024;   // partial stride (elements)
}

typedef __attribute__((ext_vector_type(4))) float f32x4;
typedef __attribute__((ext_vector_type(8))) short short8;
typedef unsigned int uint;
typedef unsigned short ushort;

// RNE split x = hi + lo (both representable as bf16; lo truncated).
__device__ inline void bsplit(float x, ushort& h, ushort& l) {
  uint u = __float_as_uint(x);
  uint hr = (u + 0x7FFFu + ((u >> 16) & 1u)) & 0xFFFF0000u;
  float lof = x - __uint_as_float(hr);
  h = (ushort)(hr >> 16);
  l = (ushort)(__float_as_uint(lof) >> 16);
}
__device__ inline uint pk(ushort a, ushort b) { return (uint)a | ((uint)b << 16); }

// async 16B global->LDS (m97-verified path)
__device__ inline void gld16(const void* g, void* l) {
  __builtin_amdgcn_global_load_lds(
      (const __attribute__((address_space(1))) uint*)g,
      (__attribute__((address_space(3))) uint*)l, 16, 0, 0);
}

// ---------------------------------------------------------------------------
// One-shot elementwise fp32 -> bf16 hi/lo split.
// ---------------------------------------------------------------------------
__global__ __launch_bounds__(256) void asplit_kernel(
    const float* __restrict__ X, ushort* __restrict__ Xh,
    ushort* __restrict__ Xl, int n8) {
  const int idx = blockIdx.x * 256 + threadIdx.x;
  if (idx >= n8) return;
  const float4 a = *(const float4*)(X + (size_t)idx * 8);
  const float4 b = *(const float4*)(X + (size_t)idx * 8 + 4);
  float f[8] = {a.x, a.y, a.z, a.w, b.x, b.y, b.z, b.w};
  short8 h, l;
#pragma unroll
  for (int j = 0; j < 8; ++j) {
    ushort hh, ll;
    bsplit(f[j], hh, ll);
    h[j] = (short)hh;
    l[j] = (short)ll;
  }
  *(short8*)(Xh + (size_t)idx * 8) = h;
  *(short8*)(Xl + (size_t)idx * 8) = l;
}

// ---------------------------------------------------------------------------
// R9: combine 2 split-K partials + bias -> bf16 hi/lo split output (K-proj).
// ---------------------------------------------------------------------------
__global__ __launch_bounds__(256) void kcombine_kernel(
    const float* __restrict__ P0, const float* __restrict__ P1,
    const float* __restrict__ bias, ushort* __restrict__ Ch,
    ushort* __restrict__ Cl, int Nc) {
  const int idx = blockIdx.x * 256 + threadIdx.x;
  const size_t base = (size_t)idx * 8;
  const int col = (int)(base & (size_t)(Nc - 1));   // Nc power of 2
  const float4 a0 = *(const float4*)(P0 + base);
  const float4 a1 = *(const float4*)(P0 + base + 4);
  const float4 b0 = *(const float4*)(P1 + base);
  const float4 b1 = *(const float4*)(P1 + base + 4);
  const float4 c0 = *(const float4*)(bias + col);
  const float4 c1 = *(const float4*)(bias + col + 4);
  float f[8] = {a0.x + b0.x + c0.x, a0.y + b0.y + c0.y,
                a0.z + b0.z + c0.z, a0.w + b0.w + c0.w,
                a1.x + b1.x + c1.x, a1.y + b1.y + c1.y,
                a1.z + b1.z + c1.z, a1.w + b1.w + c1.w};
  short8 h, l;
#pragma unroll
  for (int j = 0; j < 8; ++j) {
    ushort hh, ll;
    bsplit(f[j], hh, ll);
    h[j] = (short)hh;
    l[j] = (short)ll;
  }
  *(short8*)(Ch + base) = h;
  *(short8*)(Cl + base) = l;
}

// ---------------------------------------------------------------------------
// Weight transpose + bf16 split: W fp32 [K][N] -> Wth, Wtl bf16 [N][K].
// ---------------------------------------------------------------------------
__global__ __launch_bounds__(256) void tsplit_kernel(
    const float* __restrict__ W, ushort* __restrict__ Wth,
    ushort* __restrict__ Wtl, int K, int Nc) {
  __shared__ float S[32][33];
  const int t = threadIdx.x;
  const int n0 = blockIdx.x * 32, k0 = blockIdx.y * 32;
  const int c = t & 31, r8 = t >> 5;
#pragma unroll
  for (int i = 0; i < 4; ++i) {
    const int rr = r8 + i * 8;
    S[rr][c] = W[(size_t)(k0 + rr) * Nc + n0 + c];
  }
  __syncthreads();
#pragma unroll
  for (int i = 0; i < 4; ++i) {
    const int nn = r8 + i * 8;
    const float x = S[c][nn];
    ushort h, l;
    bsplit(x, h, l);
    const size_t o = (size_t)(n0 + nn) * K + k0 + c;
    Wth[o] = h;
    Wtl[o] = l;
  }
}

// ---------------------------------------------------------------------------
// R9 V transpose prep: reads TWO split-K partials + bias.
// V = P0+P1+bv -> Vth/Vtl bf16 [(b*H+h)*64+e][N].
// ---------------------------------------------------------------------------
__global__ __launch_bounds__(256) void vtprep2_kernel(
    const float* __restrict__ P0, const float* __restrict__ P1,
    const float* __restrict__ bias, ushort* __restrict__ Vth,
    ushort* __restrict__ Vtl) {
  __shared__ float S[64][68];
  const int t  = threadIdx.x;
  const int nt = blockIdx.x & 15;
  const int h  = (blockIdx.x >> 4) & 15;
  const int b  = blockIdx.x >> 8;
  const int n0 = nt * 64;
#pragma unroll
  for (int i = 0; i < 4; ++i) {
    const int idx = i * 256 + t;
    const int row = idx >> 4, c4 = (idx & 15) * 4;
    const size_t go = (size_t)(b * N_ + n0 + row) * HE + h * 64 + c4;
    const float4 v0 = *(const float4*)(P0 + go);
    const float4 v1 = *(const float4*)(P1 + go);
    const float4 bb = *(const float4*)(bias + h * 64 + c4);
    float4 s;
    s.x = v0.x + v1.x + bb.x;
    s.y = v0.y + v1.y + bb.y;
    s.z = v0.z + v1.z + bb.z;
    s.w = v0.w + v1.w + bb.w;
    *(float4*)&S[row][c4] = s;
  }
  __syncthreads();
  const int e = t >> 2, nch = (t & 3) * 16;
  short8 h0, h1, l0, l1;
#pragma unroll
  for (int j = 0; j < 8; ++j) {
    ushort hh, ll;
    bsplit(S[nch + j][e], hh, ll);
    h0[j] = (short)hh; l0[j] = (short)ll;
    bsplit(S[nch + 8 + j][e], hh, ll);
    h1[j] = (short)hh; l1[j] = (short)ll;
  }
  const size_t off = (size_t)((b * H_ + h) * 64 + e) * N_ + n0 + nch;
  *(short8*)(Vth + off)     = h0;
  *(short8*)(Vth + off + 8) = h1;
  *(short8*)(Vtl + off)     = l0;
  *(short8*)(Vtl + off + 8) = l1;
}

// ---------------------------------------------------------------------------
// V transpose prep (fallback path): V fp32 -> Vth/Vtl.
// ---------------------------------------------------------------------------
__global__ __launch_bounds__(256) void vtprep_kernel(
    const float* __restrict__ V, ushort* __restrict__ Vth,
    ushort* __restrict__ Vtl) {
  __shared__ float S[64][68];
  const int t  = threadIdx.x;
  const int nt = blockIdx.x & 15;
  const int h  = (blockIdx.x >> 4) & 15;
  const int b  = blockIdx.x >> 8;
  const int n0 = nt * 64;
#pragma unroll
  for (int i = 0; i < 4; ++i) {
    const int idx = i * 256 + t;
    const int row = idx >> 4, c4 = (idx & 15) * 4;
    *(float4*)&S[row][c4] =
        *(const float4*)&V[(size_t)(b * N_ + n0 + row) * HE + h * 64 + c4];
  }
  __syncthreads();
  const int e = t >> 2, nch = (t & 3) * 16;
  short8 h0, h1, l0, l1;
#pragma unroll
  for (int j = 0; j < 8; ++j) {
    ushort hh, ll;
    bsplit(S[nch + j][e], hh, ll);
    h0[j] = (short)hh; l0[j] = (short)ll;
    bsplit(S[nch + 8 + j][e], hh, ll);
    h1[j] = (short)hh; l1[j] = (short)ll;
  }
  const size_t off = (size_t)((b * H_ + h) * 64 + e) * N_ + n0 + nch;
  *(short8*)(Vth + off)     = h0;
  *(short8*)(Vth + off + 8) = h1;
  *(short8*)(Vtl + off)     = l0;
  *(short8*)(Vtl + off + 8) = l1;
}

// ---------------------------------------------------------------------------
// bf16x3 split MFMA GEMM, fp32 A converted in-loop (verified fallback path).
// ---------------------------------------------------------------------------
template <bool ROWMASK, bool SPLITOUT>
__global__ __launch_bounds__(256) void gemm_split3_kernel(
    const float* __restrict__ A, const ushort* __restrict__ Bth,
    const ushort* __restrict__ Btl, const float* __restrict__ bias,
    const float* __restrict__ rowmask, float* __restrict__ C,
    ushort* __restrict__ Ch, ushort* __restrict__ Cl, int Kd, int Nc) {
  __shared__ ushort Ah[128][32];
  __shared__ ushort Al[128][32];
  __shared__ ushort Bh[128][32];
  __shared__ ushort Bl[128][32];

  const int t    = threadIdx.x;
  const int lane = t & 63;
  const int wv   = t >> 6;
  const int l15  = lane & 15;
  const int quad = lane >> 4;
  const int wm   = (wv & 1) * 64;
  const int wn   = (wv >> 1) * 64;
  const int row0 = blockIdx.y * 128;
  const int col0 = blockIdx.x * 128;

  const int arow = t >> 1;
  const int half = t & 1;
  const float* Ap = A + (size_t)(row0 + arow) * Kd + half * 16;

  const int bn  = (lane >> 2);
  const int bk8 = (lane & 3) * 8;
  const ushort* Bhp = Bth + (size_t)(col0 + wv * 32 + bn) * Kd + bk8;
  const ushort* Blp = Btl + (size_t)(col0 + wv * 32 + bn) * Kd + bk8;

  f32x4 acc[4][4];
#pragma unroll
  for (int i = 0; i < 4; ++i)
#pragma unroll
    for (int j = 0; j < 4; ++j) acc[i][j] = {0.f, 0.f, 0.f, 0.f};

  for (int k0 = 0; k0 < Kd; k0 += 32) {
    __syncthreads();
#pragma unroll
    for (int j = 0; j < 2; ++j) {
      const int n = wv * 32 + j * 16 + bn;
      gld16(Bhp + (size_t)j * 16 * Kd + k0, &Bh[n][bk8]);
      gld16(Blp + (size_t)j * 16 * Kd + k0, &Bl[n][bk8]);
    }
    float f[16];
#pragma unroll
    for (int i = 0; i < 4; ++i) {
      const float4 v = *(const float4*)(Ap + k0 + i * 4);
      f[i * 4 + 0] = v.x; f[i * 4 + 1] = v.y;
      f[i * 4 + 2] = v.z; f[i * 4 + 3] = v.w;
    }
    ushort hh[16], ll[16];
#pragma unroll
    for (int i = 0; i < 16; ++i) bsplit(f[i], hh[i], ll[i]);
    uint4 wh0 = {pk(hh[0], hh[1]), pk(hh[2], hh[3]), pk(hh[4], hh[5]), pk(hh[6], hh[7])};
    uint4 wh1 = {pk(hh[8], hh[9]), pk(hh[10], hh[11]), pk(hh[12], hh[13]), pk(hh[14], hh[15])};
    uint4 wl0 = {pk(ll[0], ll[1]), pk(ll[2], ll[3]), pk(ll[4], ll[5]), pk(ll[6], ll[7])};
    uint4 wl1 = {pk(ll[8], ll[9]), pk(ll[10], ll[11]), pk(ll[12], ll[13]), pk(ll[14], ll[15])};
    *(uint4*)&Ah[arow][half * 16 + 0] = wh0;
    *(uint4*)&Ah[arow][half * 16 + 8] = wh1;
    *(uint4*)&Al[arow][half * 16 + 0] = wl0;
    *(uint4*)&Al[arow][half * 16 + 8] = wl1;

    __syncthreads();

    short8 ah[4], al[4], bh[4], bl[4];
#pragma unroll
    for (int mi = 0; mi < 4; ++mi) {
      ah[mi] = *(const short8*)&Ah[wm + mi * 16 + l15][quad * 8];
      al[mi] = *(const short8*)&Al[wm + mi * 16 + l15][quad * 8];
    }
#pragma unroll
    for (int ni = 0; ni < 4; ++ni) {
      bh[ni] = *(const short8*)&Bh[wn + ni * 16 + l15][quad * 8];
      bl[ni] = *(const short8*)&Bl[wn + ni * 16 + l15][quad * 8];
    }
#pragma unroll
    for (int mi = 0; mi < 4; ++mi)
#pragma unroll
      for (int ni = 0; ni < 4; ++ni) {
        acc[mi][ni] = __builtin_amdgcn_mfma_f32_16x16x32_bf16(
            ah[mi], bh[ni], acc[mi][ni], 0, 0, 0);
        acc[mi][ni] = __builtin_amdgcn_mfma_f32_16x16x32_bf16(
            ah[mi], bl[ni], acc[mi][ni], 0, 0, 0);
        acc[mi][ni] = __builtin_amdgcn_mfma_f32_16x16x32_bf16(
            al[mi], bh[ni], acc[mi][ni], 0, 0, 0);
      }
  }

  float bb[4];
#pragma unroll
  for (int ni = 0; ni < 4; ++ni) bb[ni] = bias[col0 + wn + ni * 16 + l15];
#pragma unroll
  for (int mi = 0; mi < 4; ++mi)
#pragma unroll
    for (int r = 0; r < 4; ++r) {
      const int row = row0 + wm + mi * 16 + quad * 4 + r;
      const float rm = ROWMASK ? rowmask[row] : 1.f;
#pragma unroll
      for (int ni = 0; ni < 4; ++ni) {
        const int col = col0 + wn + ni * 16 + l15;
        float v = acc[mi][ni][r] + bb[ni];
        if (SPLITOUT) {
          ushort vh, vl;
          bsplit(v, vh, vl);
          Ch[(size_t)row * Nc + col] = vh;
          Cl[(size_t)row * Nc + col] = vl;
        } else {
          if (ROWMASK) v *= rm;
          C[(size_t)row * Nc + col] = v;
        }
      }
    }
}

// ---------------------------------------------------------------------------
// bf16x3 split MFMA GEMM, BOTH operands pre-split bf16 hi/lo (R4-verified).
// ---------------------------------------------------------------------------
template <bool ROWMASK, bool SPLITOUT>
__global__ __launch_bounds__(256) void gemm_bb_kernel(
    const ushort* __restrict__ Ath, const ushort* __restrict__ Atl,
    const ushort* __restrict__ Bth, const ushort* __restrict__ Btl,
    const float* __restrict__ bias, const float* __restrict__ rowmask,
    float* __restrict__ C, ushort* __restrict__ Ch, ushort* __restrict__ Cl,
    int Kd, int Nc, int gx) {
  __shared__ ushort Ah[128][32];
  __shared__ ushort Al[128][32];
  __shared__ ushort Bh[128][32];
  __shared__ ushort Bl[128][32];

  const int t    = threadIdx.x;
  const int lane = t & 63;
  const int wv   = t >> 6;
  const int l15  = lane & 15;
  const int quad = lane >> 4;
  const int wm   = (wv & 1) * 64;
  const int wn   = (wv >> 1) * 64;

  const int lin  = blockIdx.x;
  const int xb   = (lin >> 3) % gx;
  const int yb   = (lin & 7) + 8 * ((lin >> 3) / gx);
  const int row0 = yb * 128;
  const int col0 = xb * 128;

  const int rn  = (lane >> 2);
  const int rk8 = (lane & 3) * 8;
  const ushort* Ahp = Ath + (size_t)(row0 + wv * 32 + rn) * Kd + rk8;
  const ushort* Alp = Atl + (size_t)(row0 + wv * 32 + rn) * Kd + rk8;
  const ushort* Bhp = Bth + (size_t)(col0 + wv * 32 + rn) * Kd + rk8;
  const ushort* Blp = Btl + (size_t)(col0 + wv * 32 + rn) * Kd + rk8;

  f32x4 acc[4][4];
#pragma unroll
  for (int i = 0; i < 4; ++i)
#pragma unroll
    for (int j = 0; j < 4; ++j) acc[i][j] = {0.f, 0.f, 0.f, 0.f};

  for (int k0 = 0; k0 < Kd; k0 += 32) {
    __syncthreads();
#pragma unroll
    for (int j = 0; j < 2; ++j) {
      const int rr = wv * 32 + j * 16;
      const size_t o = (size_t)j * 16 * Kd + k0;
      gld16(Ahp + o, &Ah[rr][0]);
      gld16(Alp + o, &Al[rr][0]);
      gld16(Bhp + o, &Bh[rr][0]);
      gld16(Blp + o, &Bl[rr][0]);
    }
    __syncthreads();

    short8 ah[4], al[4], bh[4], bl[4];
#pragma unroll
    for (int mi = 0; mi < 4; ++mi) {
      ah[mi] = *(const short8*)&Ah[wm + mi * 16 + l15][quad * 8];
      al[mi] = *(const short8*)&Al[wm + mi * 16 + l15][quad * 8];
    }
#pragma unroll
    for (int ni = 0; ni < 4; ++ni) {
      bh[ni] = *(const short8*)&Bh[wn + ni * 16 + l15][quad * 8];
      bl[ni] = *(const short8*)&Bl[wn + ni * 16 + l15][quad * 8];
    }
#pragma unroll
    for (int mi = 0; mi < 4; ++mi)
#pragma unroll
      for (int ni = 0; ni < 4; ++ni) {
        acc[mi][ni] = __builtin_amdgcn_mfma_f32_16x16x32_bf16(
            ah[mi], bh[ni], acc[mi][ni], 0, 0, 0);
        acc[mi][ni] = __builtin_amdgcn_mfma_f32_16x16x32_bf16(
            ah[mi], bl[ni], acc[mi][ni], 0, 0, 0);
        acc[mi][ni] = __builtin_amdgcn_mfma_f32_16x16x32_bf16(
            al[mi], bh[ni], acc[mi][ni], 0, 0, 0);
      }
  }

  float bb[4];
#pragma unroll
  for (int ni = 0; ni < 4; ++ni) bb[ni] = bias[col0 + wn + ni * 16 + l15];
#pragma unroll
  for (int mi = 0; mi < 4; ++mi)
#pragma unroll
    for (int r = 0; r < 4; ++r) {
      const int row = row0 + wm + mi * 16 + quad * 4 + r;
      const float rm = ROWMASK ? rowmask[row] : 1.f;
#pragma unroll
      for (int ni = 0; ni < 4; ++ni) {
        const int col = col0 + wn + ni * 16 + l15;
        float v = acc[mi][ni][r] + bb[ni];
        if (SPLITOUT) {
          ushort vh, vl;
          bsplit(v, vh, vl);
          Ch[(size_t)row * Nc + col] = vh;
          Cl[(size_t)row * Nc + col] = vl;
        } else {
          if (ROWMASK) v *= rm;
          C[(size_t)row * Nc + col] = v;
        }
      }
    }
}

// ---------------------------------------------------------------------------
// R9: split-K=2 variant of gemm_bb. Inner loop byte-identical; each block
// computes half the K range and writes an fp32 partial (no bias). Grid is
// 2x (1024 for K/V proj) -> 3 blocks/CU resident (VGPR allows 3 waves/SIMD;
// R4's 512-block grid was GRID-limited at 2). Partials land in the unused
// scores_out region of d_out (overwritten later by attention).
// ---------------------------------------------------------------------------
__global__ __launch_bounds__(256) void gemm_part_kernel(
    const ushort* __restrict__ Ath, const ushort* __restrict__ Atl,
    const ushort* __restrict__ Bth, const ushort* __restrict__ Btl,
    float* __restrict__ Cpart, int Kd, int KH, int Nc, int gx) {
  __shared__ ushort Ah[128][32];
  __shared__ ushort Al[128][32];
  __shared__ ushort Bh[128][32];
  __shared__ ushort Bl[128][32];

  const int t    = threadIdx.x;
  const int lane = t & 63;
  const int wv   = t >> 6;
  const int l15  = lane & 15;
  const int quad = lane >> 4;
  const int wm   = (wv & 1) * 64;
  const int wn   = (wv >> 1) * 64;

  // decode: ks (K-half) interleaved in bit 0; rest XCD-aware as gemm_bb
  const int lin  = blockIdx.x;
  const int ks   = lin & 1;
  const int rest = lin >> 1;
  const int xb   = (rest >> 3) % gx;
  const int yb   = (rest & 7) + 8 * ((rest >> 3) / gx);
  const int row0 = yb * 128;
  const int col0 = xb * 128;

  const int rn  = (lane >> 2);
  const int rk8 = (lane & 3) * 8;
  const ushort* Ahp = Ath + (size_t)(row0 + wv * 32 + rn) * Kd + rk8;
  const ushort* Alp = Atl + (size_t)(row0 + wv * 32 + rn) * Kd + rk8;
  const ushort* Bhp = Bth + (size_t)(col0 + wv * 32 + rn) * Kd + rk8;
  const ushort* Blp = Btl + (size_t)(col0 + wv * 32 + rn) * Kd + rk8;

  f32x4 acc[4][4];
#pragma unroll
  for (int i = 0; i < 4; ++i)
#pragma unroll
    for (int j = 0; j < 4; ++j) acc[i][j] = {0.f, 0.f, 0.f, 0.f};

  const int kbeg = ks * KH;
  for (int k0 = kbeg; k0 < kbeg + KH; k0 += 32) {
    __syncthreads();
#pragma unroll
    for (int j = 0; j < 2; ++j) {
      const int rr = wv * 32 + j * 16;
      const size_t o = (size_t)j * 16 * Kd + k0;
      gld16(Ahp + o, &Ah[rr][0]);
      gld16(Alp + o, &Al[rr][0]);
      gld16(Bhp + o, &Bh[rr][0]);
      gld16(Blp + o, &Bl[rr][0]);
    }
    __syncthreads();

    short8 ah[4], al[4], bh[4], bl[4];
#pragma unroll
    for (int mi = 0; mi < 4; ++mi) {
      ah[mi] = *(const short8*)&Ah[wm + mi * 16 + l15][quad * 8];
      al[mi] = *(const short8*)&Al[wm + mi * 16 + l15][quad * 8];
    }
#pragma unroll
    for (int ni = 0; ni < 4; ++ni) {
      bh[ni] = *(const short8*)&Bh[wn + ni * 16 + l15][quad * 8];
      bl[ni] = *(const short8*)&Bl[wn + ni * 16 + l15][quad * 8];
    }
#pragma unroll
    for (int mi = 0; mi < 4; ++mi)
#pragma unroll
      for (int ni = 0; ni < 4; ++ni) {
        acc[mi][ni] = __builtin_amdgcn_mfma_f32_16x16x32_bf16(
            ah[mi], bh[ni], acc[mi][ni], 0, 0, 0);
        acc[mi][ni] = __builtin_amdgcn_mfma_f32_16x16x32_bf16(
            ah[mi], bl[ni], acc[mi][ni], 0, 0, 0);
        acc[mi][ni] = __builtin_amdgcn_mfma_f32_16x16x32_bf16(
            al[mi], bh[ni], acc[mi][ni], 0, 0, 0);
      }
  }

  float* Cp = Cpart + (size_t)ks * PST;
#pragma unroll
  for (int mi = 0; mi < 4; ++mi)
#pragma unroll
    for (int r = 0; r < 4; ++r) {
      const int row = row0 + wm + mi * 16 + quad * 4 + r;
#pragma unroll
      for (int ni = 0; ni < 4; ++ni) {
        const int col = col0 + wn + ni * 16 + l15;
        Cp[(size_t)row * Nc + col] = acc[mi][ni][r];
      }
    }
}

// ---------------------------------------------------------------------------
// MFMA flash attention. Block = (b, h, 64 q-rows); 4 waves x 16 rows.
// ---------------------------------------------------------------------------
__global__ __launch_bounds__(256) void attn_mfma_kernel(
    const ushort* __restrict__ Qh, const ushort* __restrict__ Ql,
    const ushort* __restrict__ Kh, const ushort* __restrict__ Kl,
    const ushort* __restrict__ Vth, const ushort* __restrict__ Vtl,
    const unsigned char* __restrict__ kvmask, const float* __restrict__ tsmask,
    float* __restrict__ outv, float* __restrict__ scores_out) {
  __shared__ __align__(16) ushort sm[24576];  // 48 KB
  ushort* KHT = sm;
  ushort* KLT = sm + 4096;
  ushort* VTH = sm + 8192;
  ushort* VTL = sm + 12288;
  ushort* QHT = sm + 16384;
  ushort* QLT = sm + 20480;

  const int t = threadIdx.x, lane = t & 63, wv = t >> 6;
  const int l15 = lane & 15, quad = lane >> 4;
  const int blk = blockIdx.x;
  const int mt = blk & 7;
  const int h  = (blk >> 3) & 15;
  const int b  = blk >> 7;
  const int m0 = mt * 64;
  const int lrow = lane >> 3, lch = lane & 7;
  const int gch8 = (lch ^ (lrow & 7)) * 8;

#pragma unroll
  for (int i = 0; i < 2; ++i) {
    const int rr = wv * 16 + i * 8;
    const size_t g = (size_t)(b * M_ + m0 + rr + lrow) * HE + h * 64 + gch8;
    gld16(Qh + g, &QHT[rr * 64]);
    gld16(Ql + g, &QLT[rr * 64]);
  }
  __syncthreads();

  short8 qh[2], ql[2];
#pragma unroll
  for (int ks = 0; ks < 2; ++ks) {
    const int row = wv * 16 + l15;
    const int off = row * 64 + (((ks * 4 + quad) ^ (row & 7)) << 3);
    qh[ks] = *(const short8*)&QHT[off];
    ql[ks] = *(const short8*)&QLT[off];
  }
  __builtin_amdgcn_s_waitcnt(0);

  uint* Pu = (uint*)(sm + 16384) + wv * 1024;

  float tsm_v[4];
#pragma unroll
  for (int r = 0; r < 4; ++r)
    tsm_v[r] = tsmask[b * M_ + m0 + wv * 16 + quad * 4 + r];

  float m_i[4] = {-INFINITY, -INFINITY, -INFINITY, -INFINITY};
  float l_i[4] = {0.f, 0.f, 0.f, 0.f};
  f32x4 acc[4];
#pragma unroll
  for (int es = 0; es < 4; ++es) acc[es] = {0.f, 0.f, 0.f, 0.f};

  for (int nc = 0; nc < 16; ++nc) {
    const int n0 = nc * 64;
    __syncthreads();
#pragma unroll
    for (int i = 0; i < 2; ++i) {
      const int rr = wv * 16 + i * 8;
      const size_t gk = (size_t)(b * N_ + n0 + rr + lrow) * HE + h * 64 + gch8;
      const size_t gv = (size_t)((b * H_ + h) * 64 + rr + lrow) * N_ + n0 + gch8;
      gld16(Kh + gk, &KHT[rr * 64]);
      gld16(Kl + gk, &KLT[rr * 64]);
      gld16(Vth + gv, &VTH[rr * 64]);
      gld16(Vtl + gv, &VTL[rr * 64]);
    }
    __syncthreads();

    f32x4 s[4];
#pragma unroll
    for (int ns = 0; ns < 4; ++ns) {
      s[ns] = {0.f, 0.f, 0.f, 0.f};
#pragma unroll
      for (int ks = 0; ks < 2; ++ks) {
        const int row = ns * 16 + l15;
        const int off = row * 64 + (((ks * 4 + quad) ^ (row & 7)) << 3);
        const short8 kh = *(const short8*)&KHT[off];
        const short8 kl = *(const short8*)&KLT[off];
        s[ns] = __builtin_amdgcn_mfma_f32_16x16x32_bf16(qh[ks], kh, s[ns], 0, 0, 0);
        s[ns] = __builtin_amdgcn_mfma_f32_16x16x32_bf16(qh[ks], kl, s[ns], 0, 0, 0);
        s[ns] = __builtin_amdgcn_mfma_f32_16x16x32_bf16(ql[ks], kh, s[ns], 0, 0, 0);
      }
    }

    bool km[4];
#pragma unroll
    for (int ns = 0; ns < 4; ++ns)
      km[ns] = kvmask[b * N_ + n0 + ns * 16 + l15] != 0;
    float sc[4][4];
#pragma unroll
    for (int ns = 0; ns < 4; ++ns)
#pragma unroll
      for (int r = 0; r < 4; ++r)
        sc[r][ns] = km[ns] ? -INFINITY : s[ns][r] * 0.125f;

#pragma unroll
    for (int r = 0; r < 4; ++r) {
      const size_t base =
          ((size_t)(b * H_ + h) * M_ + m0 + wv * 16 + quad * 4 + r) * N_ + n0;
      const bool vr = tsm_v[r] != 0.f;
#pragma unroll
      for (int ns = 0; ns < 4; ++ns)
        scores_out[base + ns * 16 + l15] =
            (vr && !km[ns]) ? sc[r][ns] : NEG_BIG;
    }

#pragma unroll
    for (int r = 0; r < 4; ++r) {
      float cm = fmaxf(fmaxf(sc[r][0], sc[r][1]), fmaxf(sc[r][2], sc[r][3]));
#pragma unroll
      for (int o = 1; o < 16; o <<= 1) cm = fmaxf(cm, __shfl_xor(cm, o));
      const float nm = fmaxf(m_i[r], cm);
      const float alpha = (m_i[r] == -INFINITY) ? 0.f : __expf(m_i[r] - nm);
      float ps = 0.f;
      const int pr = quad * 4 + r;
#pragma unroll
      for (int ns = 0; ns < 4; ++ns) {
        const float p = (sc[r][ns] == -INFINITY) ? 0.f : __expf(sc[r][ns] - nm);
        ps += p;
        ushort ph_, pl_;
        bsplit(p, ph_, pl_);
        const int c = ns * 16 + l15;
        Pu[pr * 64 + (((c >> 2) ^ (pr & 7)) << 2) + (c & 3)] = pk(ph_, pl_);
      }
#pragma unroll
      for (int o = 1; o < 16; o <<= 1) ps += __shfl_xor(ps, o);
      l_i[r] = l_i[r] * alpha + ps;
      m_i[r] = nm;
#pragma unroll
      for (int es = 0; es < 4; ++es) acc[es][r] *= alpha;
    }

#pragma unroll
    for (int ks = 0; ks < 2; ++ks) {
      const int c0 = ks * 8 + quad * 2;
      const uint* pb = &Pu[l15 * 64];
      const uint4 u0 = *(const uint4*)&pb[(c0 ^ (l15 & 7)) << 2];
      const uint4 u1 = *(const uint4*)&pb[((c0 + 1) ^ (l15 & 7)) << 2];
      short8 ph, pl;
      const uint* up0 = (const uint*)&u0;
      const uint* up1 = (const uint*)&u1;
#pragma unroll
      for (int j = 0; j < 4; ++j) {
        ph[j] = (short)(up0[j] & 0xffffu); pl[j] = (short)(up0[j] >> 16);
        ph[4 + j] = (short)(up1[j] & 0xffffu); pl[4 + j] = (short)(up1[j] >> 16);
      }
#pragma unroll
      for (int es = 0; es < 4; ++es) {
        const int row = es * 16 + l15;
        const int off = row * 64 + (((ks * 4 + quad) ^ (row & 7)) << 3);
        const short8 vh = *(const short8*)&VTH[off];
        const short8 vl = *(const short8*)&VTL[off];
        acc[es] = __builtin_amdgcn_mfma_f32_16x16x32_bf16(ph, vh, acc[es], 0, 0, 0);
        acc[es] = __builtin_amdgcn_mfma_f32_16x16x32_bf16(ph, vl, acc[es], 0, 0, 0);
        acc[es] = __builtin_amdgcn_mfma_f32_16x16x32_bf16(pl, vh, acc[es], 0, 0, 0);
      }
    }
  }

#pragma unroll
  for (int r = 0; r < 4; ++r) {
    const float inv = (l_i[r] > 0.f) ? 1.f / l_i[r] : 0.f;
    const int grow = b * M_ + m0 + wv * 16 + quad * 4 + r;
#pragma unroll
    for (int es = 0; es < 4; ++es)
      outv[(size_t)grow * HE + h * 64 + es * 16 + l15] = acc[es][r] * inv;
  }
}

// ---------------------------------------------------------------------------
extern "C" void kernel_launch(void* const* d_in, const int* in_sizes, int n_in,
                              void* d_out, int out_size, void* d_ws,
                              size_t ws_size, hipStream_t stream) {
  const float* ts  = (const float*)d_in[0];
  const float* kv  = (const float*)d_in[1];
  const float* tsm = (const float*)d_in[2];
  const unsigned char* kvm = (const unsigned char*)d_in[3];
  const float* Wq = (const float*)d_in[4];
  const float* bq = (const float*)d_in[5];
  const float* Wk = (const float*)d_in[6];
  const float* bk = (const float*)d_in[7];
  const float* Wv = (const float*)d_in[8];
  const float* bv = (const float*)d_in[9];
  const float* Wo = (const float*)d_in[10];
  const float* bo = (const float*)d_in[11];

  float* out        = (float*)d_out;
  float* scores_out = out + (size_t)B_ * M_ * DLLM;

  char* ws = (char*)d_ws;
  constexpr size_t MB = 1024 * 1024;

  if (ws_size >= 260 * MB) {
    // ---------- pre-split path ----------
    ushort* Kvh  = (ushort*)(ws);
    ushort* Kvl  = (ushort*)(ws + 64 * MB);
    ushort* Khp  = (ushort*)(ws + 160 * MB);
    ushort* Klp  = (ushort*)(ws + 176 * MB);
    ushort* Qhp  = (ushort*)(ws + 192 * MB);
    ushort* Qlp  = (ushort*)(ws + 200 * MB);
    ushort* Tsh  = (ushort*)(ws + 208 * MB);
    ushort* Tsl  = (ushort*)(ws + 216 * MB);
    ushort* Wqh  = (ushort*)(ws + 224 * MB);
    ushort* Wql  = (ushort*)(ws + 226 * MB);
    ushort* Wkh  = (ushort*)(ws + 228 * MB);
    ushort* Wkl  = (ushort*)(ws + 236 * MB);
    ushort* Wvh  = (ushort*)(ws + 244 * MB);
    ushort* Wvl  = (ushort*)(ws + 252 * MB);
    // aliases valid once predecessors are dead (stream-ordered)
    ushort* Vthp  = (ushort*)(ws);
    ushort* Vtlp  = (ushort*)(ws + 16 * MB);
    ushort* outvh = (ushort*)(ws + 32 * MB);
    ushort* outvl = (ushort*)(ws + 40 * MB);
    ushort* Woh   = (ushort*)(ws + 64 * MB);
    ushort* Wol   = (ushort*)(ws + 72 * MB);
    float*  outv  = (float*)(ws + 128 * MB);

    // split-K partials live in the scores_out region of d_out (256 MB),
    // which is only written by attention (later in the stream).
    float* Kp = scores_out;              // [2][8192][1024] fp32 = 64 MB
    float* Vp = scores_out + 2 * PST;    // [2][8192][1024] fp32 = 64 MB

    // input pre-splits
    {
      const int n8_ts = (B_ * M_ * DTS) / 8;
      asplit_kernel<<<dim3(n8_ts / 256), 256, 0, stream>>>(ts, Tsh, Tsl, n8_ts);
      const int n8_kv = (B_ * N_ * DLLM) / 8;
      asplit_kernel<<<dim3(n8_kv / 256), 256, 0, stream>>>(kv, Kvh, Kvl, n8_kv);
    }

    // weight transpose+split
    tsplit_kernel<<<dim3(HE / 32, DTS / 32), 256, 0, stream>>>(Wq, Wqh, Wql, DTS, HE);
    tsplit_kernel<<<dim3(HE / 32, DLLM / 32), 256, 0, stream>>>(Wk, Wkh, Wkl, DLLM, HE);
    tsplit_kernel<<<dim3(HE / 32, DLLM / 32), 256, 0, stream>>>(Wv, Wvh, Wvl, DLLM, HE);

    // Q projection (unchanged)
    gemm_bb_kernel<false, true><<<dim3((HE / 128) * ((B_ * M_) / 128)), 256, 0, stream>>>(
        Tsh, Tsl, Wqh, Wql, bq, nullptr, nullptr, Qhp, Qlp, DTS, HE, HE / 128);

    // K / V projections: split-K=2, fp32 partials (grid 1024 -> 3 blocks/CU)
    gemm_part_kernel<<<dim3(2 * (HE / 128) * ((B_ * N_) / 128)), 256, 0, stream>>>(
        Kvh, Kvl, Wkh, Wkl, Kp, DLLM, DLLM / 2, HE, HE / 128);
    gemm_part_kernel<<<dim3(2 * (HE / 128) * ((B_ * N_) / 128)), 256, 0, stream>>>(
        Kvh, Kvl, Wvh, Wvl, Vp, DLLM, DLLM / 2, HE, HE / 128);

    // combine K partials + bias -> split bf16
    kcombine_kernel<<<dim3((B_ * N_ * HE / 8) / 256), 256, 0, stream>>>(
        Kp, Kp + PST, bk, Khp, Klp, HE);

    // V^T split prep from V partials (+bias); writes into [0,32) (Kv dead)
    vtprep2_kernel<<<dim3(B_ * H_ * 16), 256, 0, stream>>>(
        Vp, Vp + PST, bv, Vthp, Vtlp);

    // MFMA flash attention (+ scores_for_log; overwrites partial scratch)
    attn_mfma_kernel<<<dim3(B_ * H_ * (M_ / 64)), 256, 0, stream>>>(
        Qhp, Qlp, Khp, Klp, Vthp, Vtlp, kvm, tsm, outv, scores_out);

    // split attn output for pre-split O-GEMM
    {
      const int n8_o = (B_ * M_ * HE) / 8;
      asplit_kernel<<<dim3(n8_o / 256), 256, 0, stream>>>(outv, outvh, outvl, n8_o);
    }

    // output projection (unchanged)
    tsplit_kernel<<<dim3(DLLM / 32, HE / 32), 256, 0, stream>>>(Wo, Woh, Wol, HE, DLLM);
    gemm_bb_kernel<true, false><<<dim3((DLLM / 128) * ((B_ * M_) / 128)), 256, 0, stream>>>(
        outvh, outvl, Woh, Wol, bo, tsm, out, nullptr, nullptr, HE, DLLM, DLLM / 128);
  } else {
    // ---------- fallback: exact verified baseline path (116 MB) ----------
    float*  Vf   = (float*)(ws);
    float*  outv = (float*)(ws);
    ushort* Qhp  = (ushort*)(ws + 32 * MB);
    ushort* Qlp  = (ushort*)(ws + 40 * MB);
    ushort* Khp  = (ushort*)(ws + 48 * MB);
    ushort* Klp  = (ushort*)(ws + 64 * MB);
    ushort* Wqh  = (ushort*)(ws + 80 * MB);
    ushort* Wql  = (ushort*)(ws + 82 * MB);
    ushort* Wkh  = (ushort*)(ws + 84 * MB);
    ushort* Wkl  = (ushort*)(ws + 92 * MB);
    ushort* Wvh  = (ushort*)(ws + 100 * MB);
    ushort* Wvl  = (ushort*)(ws + 108 * MB);
    ushort* Vthp = (ushort*)(ws + 84 * MB);
    ushort* Vtlp = (ushort*)(ws + 100 * MB);
    ushort* Woh  = (ushort*)(ws + 48 * MB);
    ushort* Wol  = (ushort*)(ws + 56 * MB);

    tsplit_kernel<<<dim3(HE / 32, DTS / 32), 256, 0, stream>>>(Wq, Wqh, Wql, DTS, HE);
    tsplit_kernel<<<dim3(HE / 32, DLLM / 32), 256, 0, stream>>>(Wk, Wkh, Wkl, DLLM, HE);
    tsplit_kernel<<<dim3(HE / 32, DLLM / 32), 256, 0, stream>>>(Wv, Wvh, Wvl, DLLM, HE);

    gemm_split3_kernel<false, true><<<dim3(HE / 128, (B_ * M_) / 128), 256, 0, stream>>>(
        ts, Wqh, Wql, bq, nullptr, nullptr, Qhp, Qlp, DTS, HE);
    gemm_split3_kernel<false, true><<<dim3(HE / 128, (B_ * N_) / 128), 256, 0, stream>>>(
        kv, Wkh, Wkl, bk, nullptr, nullptr, Khp, Klp, DLLM, HE);
    gemm_split3_kernel<false, false><<<dim3(HE / 128, (B_ * N_) / 128), 256, 0, stream>>>(
        kv, Wvh, Wvl, bv, nullptr, Vf, nullptr, nullptr, DLLM, HE);

    vtprep_kernel<<<dim3(B_ * H_ * 16), 256, 0, stream>>>(Vf, Vthp, Vtlp);

    attn_mfma_kernel<<<dim3(B_ * H_ * (M_ / 64)), 256, 0, stream>>>(
        Qhp, Qlp, Khp, Klp, Vthp, Vtlp, kvm, tsm, outv, scores_out);

    tsplit_kernel<<<dim3(DLLM / 32, HE / 32), 256, 0, stream>>>(Wo, Woh, Wol, HE, DLLM);
    gemm_split3_kernel<true, false><<<dim3(DLLM / 128, (B_ * M_) / 128), 256, 0, stream>>>(
        outv, Woh, Wol, bo, tsm, out, nullptr, nullptr, HE, DLLM);
  }
}